// Round 1
// baseline (2822.556 us; speedup 1.0000x reference)
//
#include <hip/hip_runtime.h>
#include <hip/hip_bf16.h>

#define T_TOK 4096
#define HDIM 1024
#define IDIM 4096
#define NEXP 8

typedef __bf16 bf16x8 __attribute__((ext_vector_type(8)));
typedef float f32x4 __attribute__((ext_vector_type(4)));

__device__ __forceinline__ unsigned short f2bf(float f) {
    union { float f; unsigned int u; } v; v.f = f;
    unsigned int u = v.u;
    unsigned int r = u + 0x7fffu + ((u >> 16) & 1u);
    return (unsigned short)(r >> 16);
}
__device__ __forceinline__ float bf2f(unsigned short b) {
    union { unsigned int u; float f; } v; v.u = ((unsigned int)b) << 16;
    return v.f;
}

// ---------------- Kernel 1: LN stats + router top-2 + routing lists ----------------
__global__ __launch_bounds__(256) void k_ln_router(
    const float* __restrict__ x, const float* __restrict__ rlw, const float* __restrict__ rlb,
    const float* __restrict__ rw, const float* __restrict__ rb,
    unsigned short* __restrict__ xhat, int* __restrict__ counts,
    int* __restrict__ ltok, float* __restrict__ lwt)
{
    const int t = blockIdx.x, tid = threadIdx.x;
    const float4 v = *(const float4*)(x + (size_t)t * HDIM + tid * 4);
    float s  = v.x + v.y + v.z + v.w;
    float sq = v.x*v.x + v.y*v.y + v.z*v.z + v.w*v.w;
    for (int o = 32; o > 0; o >>= 1) { s += __shfl_xor(s, o); sq += __shfl_xor(sq, o); }
    __shared__ float red[8];
    __shared__ float stats[2];
    const int wid = tid >> 6, lane = tid & 63;
    if (lane == 0) { red[wid] = s; red[4 + wid] = sq; }
    __syncthreads();
    if (tid == 0) {
        float S = red[0] + red[1] + red[2] + red[3];
        float Q = red[4] + red[5] + red[6] + red[7];
        float mu = S / (float)HDIM;
        float var = Q / (float)HDIM - mu * mu;
        stats[0] = mu; stats[1] = rsqrtf(var + 1e-5f);
    }
    __syncthreads();
    const float mu = stats[0], rstd = stats[1];
    float xh[4];
    xh[0] = (v.x - mu) * rstd; xh[1] = (v.y - mu) * rstd;
    xh[2] = (v.z - mu) * rstd; xh[3] = (v.w - mu) * rstd;
    ushort4 o4;
    o4.x = f2bf(xh[0]); o4.y = f2bf(xh[1]); o4.z = f2bf(xh[2]); o4.w = f2bf(xh[3]);
    *(ushort4*)(xhat + (size_t)t * HDIM + tid * 4) = o4;

    // router partials (fp32 xhat for selection fidelity)
    float p[8];
    #pragma unroll
    for (int e = 0; e < 8; e++) p[e] = 0.f;
    const float4 w4 = *(const float4*)(rlw + tid * 4);
    const float4 b4 = *(const float4*)(rlb + tid * 4);
    const float wl[4] = { w4.x, w4.y, w4.z, w4.w };
    const float bl[4] = { b4.x, b4.y, b4.z, b4.w };
    #pragma unroll
    for (int j = 0; j < 4; j++) {
        float rl = xh[j] * wl[j] + bl[j];
        const float* wr = rw + (size_t)(tid * 4 + j) * 8;
        float4 wa = *(const float4*)(wr);
        float4 wb = *(const float4*)(wr + 4);
        p[0] += rl * wa.x; p[1] += rl * wa.y; p[2] += rl * wa.z; p[3] += rl * wa.w;
        p[4] += rl * wb.x; p[5] += rl * wb.y; p[6] += rl * wb.z; p[7] += rl * wb.w;
    }
    #pragma unroll
    for (int e = 0; e < 8; e++)
        for (int o = 32; o > 0; o >>= 1) p[e] += __shfl_xor(p[e], o);
    __shared__ float pw[4][8];
    if (lane == 0) {
        #pragma unroll
        for (int e = 0; e < 8; e++) pw[wid][e] = p[e];
    }
    __syncthreads();
    if (tid == 0) {
        float lg[8];
        #pragma unroll
        for (int e = 0; e < 8; e++)
            lg[e] = pw[0][e] + pw[1][e] + pw[2][e] + pw[3][e] + rb[e];
        int i0 = 0;
        #pragma unroll
        for (int e = 1; e < 8; e++) if (lg[e] > lg[i0]) i0 = e;
        int i1 = (i0 == 0) ? 1 : 0;
        #pragma unroll
        for (int e = 0; e < 8; e++) if (e != i0 && lg[e] > lg[i1]) i1 = e;
        float e1 = expf(lg[i1] - lg[i0]);
        float w0 = 1.f / (1.f + e1);
        float w1 = 1.f - w0;
        int p0 = atomicAdd(&counts[i0], 1);
        ltok[i0 * T_TOK + p0] = t * 2 + 0; lwt[i0 * T_TOK + p0] = w0;
        int p1 = atomicAdd(&counts[i1], 1);
        ltok[i1 * T_TOK + p1] = t * 2 + 1; lwt[i1 * T_TOK + p1] = w1;
    }
}

// ---------------- Kernel 2: tiny prefix sum ----------------
__global__ void k_offs(const int* __restrict__ counts, int* __restrict__ offs) {
    if (threadIdx.x == 0 && blockIdx.x == 0) {
        int a = 0;
        for (int e = 0; e < NEXP; e++) { offs[e] = a; a += counts[e]; }
        offs[NEXP] = a;
    }
}

// ---------------- Kernel 3: grouped GEMM1 (xhat*lnW+lnB) @ w1 -> gelu -> h ----------------
__global__ __launch_bounds__(256) void k_gemm1(
    const unsigned short* __restrict__ xhat, const float* __restrict__ elw, const float* __restrict__ elb,
    const float* __restrict__ w1, const float* __restrict__ b1,
    const int* __restrict__ counts, const int* __restrict__ offs, const int* __restrict__ ltok,
    unsigned short* __restrict__ hbuf)
{
    const int e = blockIdx.z, rt = blockIdx.x, ct = blockIdx.y;
    const int ne = counts[e];
    if (rt * 128 >= ne) return;
    const int off = offs[e];
    __shared__ unsigned short As[128][72];
    __shared__ unsigned short Bs[128][72];
    __shared__ int toks[128];
    const int tid = threadIdx.x;
    if (tid < 128) {
        int r = rt * 128 + tid;
        toks[tid] = (r < ne) ? (ltok[e * T_TOK + r] >> 1) : -1;
    }
    __syncthreads();

    f32x4 acc[4][4];
    #pragma unroll
    for (int i = 0; i < 4; i++)
        #pragma unroll
        for (int j = 0; j < 4; j++) acc[i][j] = (f32x4){0.f, 0.f, 0.f, 0.f};

    const int wid = tid >> 6, lane = tid & 63;
    const int wm = (wid & 1) * 64, wn = (wid >> 1) * 64;
    const int fr = lane & 15, quad = lane >> 4;
    const float* w1e = w1 + (size_t)e * HDIM * IDIM;
    const int am = tid >> 1, akh = (tid & 1) * 32;
    const int atok = toks[am];

    for (int k0 = 0; k0 < HDIM; k0 += 64) {
        // stage A (gather + expert-LN affine -> bf16)
        {
            const int kg = k0 + akh;
            if (atok >= 0) {
                const unsigned short* src = xhat + (size_t)atok * HDIM + kg;
                const float* wv = elw + (size_t)e * HDIM + kg;
                const float* bv = elb + (size_t)e * HDIM + kg;
                #pragma unroll
                for (int j = 0; j < 32; j += 4) {
                    ushort4 xv = *(const ushort4*)(src + j);
                    float4 wf = *(const float4*)(wv + j);
                    float4 bf = *(const float4*)(bv + j);
                    ushort4 o;
                    o.x = f2bf(bf2f(xv.x) * wf.x + bf.x);
                    o.y = f2bf(bf2f(xv.y) * wf.y + bf.y);
                    o.z = f2bf(bf2f(xv.z) * wf.z + bf.z);
                    o.w = f2bf(bf2f(xv.w) * wf.w + bf.w);
                    *(ushort4*)&As[am][akh + j] = o;
                }
            } else {
                ushort4 z; z.x = z.y = z.z = z.w = 0;
                #pragma unroll
                for (int j = 0; j < 32; j += 4) *(ushort4*)&As[am][akh + j] = z;
            }
        }
        // stage B (w1 fp32 -> bf16, transpose to [n][k])
        #pragma unroll
        for (int i = 0; i < 8; i++) {
            int l = (i * 256 + tid) * 4;
            int n = l & 127, k = l >> 7;
            float4 wv = *(const float4*)(w1e + (size_t)(k0 + k) * IDIM + ct * 128 + n);
            Bs[n + 0][k] = f2bf(wv.x);
            Bs[n + 1][k] = f2bf(wv.y);
            Bs[n + 2][k] = f2bf(wv.z);
            Bs[n + 3][k] = f2bf(wv.w);
        }
        __syncthreads();
        #pragma unroll
        for (int ks = 0; ks < 64; ks += 32) {
            bf16x8 af[4], bfr[4];
            #pragma unroll
            for (int i = 0; i < 4; i++)
                __builtin_memcpy(&af[i], &As[wm + i * 16 + fr][ks + quad * 8], 16);
            #pragma unroll
            for (int j = 0; j < 4; j++)
                __builtin_memcpy(&bfr[j], &Bs[wn + j * 16 + fr][ks + quad * 8], 16);
            #pragma unroll
            for (int i = 0; i < 4; i++)
                #pragma unroll
                for (int j = 0; j < 4; j++)
                    acc[i][j] = __builtin_amdgcn_mfma_f32_16x16x32_bf16(af[i], bfr[j], acc[i][j], 0, 0, 0);
        }
        __syncthreads();
    }
    // epilogue: + b1, exact gelu, -> bf16 h
    #pragma unroll
    for (int j = 0; j < 4; j++) {
        const int n = ct * 128 + wn + j * 16 + fr;
        const float bias = b1[e * IDIM + n];
        #pragma unroll
        for (int i = 0; i < 4; i++) {
            const int mbase = rt * 128 + wm + i * 16 + quad * 4;
            #pragma unroll
            for (int rg = 0; rg < 4; rg++) {
                const int r = mbase + rg;
                if (r < ne) {
                    float v = acc[i][j][rg] + bias;
                    float g = 0.5f * v * (1.f + erff(v * 0.70710678118654752f));
                    hbuf[(size_t)(off + r) * IDIM + n] = f2bf(g);
                }
            }
        }
    }
}

// ---------------- Kernel 4: grouped GEMM2 h @ w2 -> *weight -> eo[t,slot,:] ----------------
__global__ __launch_bounds__(256) void k_gemm2(
    const unsigned short* __restrict__ hbuf, const float* __restrict__ w2, const float* __restrict__ b2,
    const int* __restrict__ counts, const int* __restrict__ offs,
    const int* __restrict__ ltok, const float* __restrict__ lwt,
    float* __restrict__ eo)
{
    const int e = blockIdx.z, rt = blockIdx.x, ct = blockIdx.y;
    const int ne = counts[e];
    if (rt * 128 >= ne) return;
    const int off = offs[e];
    __shared__ unsigned short As[128][72];
    __shared__ unsigned short Bs[128][72];
    __shared__ int dst[128];
    __shared__ float wts[128];
    const int tid = threadIdx.x;
    if (tid < 128) {
        int r = rt * 128 + tid;
        if (r < ne) { dst[tid] = ltok[e * T_TOK + r]; wts[tid] = lwt[e * T_TOK + r]; }
        else { dst[tid] = -1; wts[tid] = 0.f; }
    }
    __syncthreads();

    f32x4 acc[4][4];
    #pragma unroll
    for (int i = 0; i < 4; i++)
        #pragma unroll
        for (int j = 0; j < 4; j++) acc[i][j] = (f32x4){0.f, 0.f, 0.f, 0.f};

    const int wid = tid >> 6, lane = tid & 63;
    const int wm = (wid & 1) * 64, wn = (wid >> 1) * 64;
    const int fr = lane & 15, quad = lane >> 4;
    const float* w2e = w2 + (size_t)e * IDIM * HDIM;
    const int am = tid >> 1, akh = (tid & 1) * 32;
    const bool avalid = (dst[am] >= 0);
    const unsigned short* asrc = avalid ? (hbuf + (size_t)(off + rt * 128 + am) * IDIM + akh) : nullptr;

    for (int k0 = 0; k0 < IDIM; k0 += 64) {
        // stage A (copy bf16 h rows)
        if (avalid) {
            const unsigned short* src = asrc + k0;
            #pragma unroll
            for (int j = 0; j < 32; j += 4)
                *(ushort4*)&As[am][akh + j] = *(const ushort4*)(src + j);
        } else {
            ushort4 z; z.x = z.y = z.z = z.w = 0;
            #pragma unroll
            for (int j = 0; j < 32; j += 4) *(ushort4*)&As[am][akh + j] = z;
        }
        // stage B (w2 fp32 -> bf16, transpose to [n][k])
        #pragma unroll
        for (int i = 0; i < 8; i++) {
            int l = (i * 256 + tid) * 4;
            int n = l & 127, k = l >> 7;
            float4 wv = *(const float4*)(w2e + (size_t)(k0 + k) * HDIM + ct * 128 + n);
            Bs[n + 0][k] = f2bf(wv.x);
            Bs[n + 1][k] = f2bf(wv.y);
            Bs[n + 2][k] = f2bf(wv.z);
            Bs[n + 3][k] = f2bf(wv.w);
        }
        __syncthreads();
        #pragma unroll
        for (int ks = 0; ks < 64; ks += 32) {
            bf16x8 af[4], bfr[4];
            #pragma unroll
            for (int i = 0; i < 4; i++)
                __builtin_memcpy(&af[i], &As[wm + i * 16 + fr][ks + quad * 8], 16);
            #pragma unroll
            for (int j = 0; j < 4; j++)
                __builtin_memcpy(&bfr[j], &Bs[wn + j * 16 + fr][ks + quad * 8], 16);
            #pragma unroll
            for (int i = 0; i < 4; i++)
                #pragma unroll
                for (int j = 0; j < 4; j++)
                    acc[i][j] = __builtin_amdgcn_mfma_f32_16x16x32_bf16(af[i], bfr[j], acc[i][j], 0, 0, 0);
        }
        __syncthreads();
    }
    // epilogue: + b2, * routing weight, scatter fp32 to eo[token*2+slot]
    #pragma unroll
    for (int j = 0; j < 4; j++) {
        const int n = ct * 128 + wn + j * 16 + fr;
        const float bias = b2[e * HDIM + n];
        #pragma unroll
        for (int i = 0; i < 4; i++) {
            const int mbase = wm + i * 16 + quad * 4;
            #pragma unroll
            for (int rg = 0; rg < 4; rg++) {
                const int m = mbase + rg;
                const int d = dst[m];
                if (d >= 0) {
                    float v = (acc[i][j][rg] + bias) * wts[m];
                    eo[(size_t)d * HDIM + n] = v;
                }
            }
        }
    }
}

// ---------------- Kernel 5: combine + final LN ----------------
__global__ __launch_bounds__(256) void k_final(
    const float* __restrict__ eo, const float* __restrict__ ow, const float* __restrict__ ob,
    float* __restrict__ out)
{
    const int t = blockIdx.x, tid = threadIdx.x;
    const float4 a = *(const float4*)(eo + (size_t)(t * 2 + 0) * HDIM + tid * 4);
    const float4 b = *(const float4*)(eo + (size_t)(t * 2 + 1) * HDIM + tid * 4);
    float c0 = a.x + b.x, c1 = a.y + b.y, c2 = a.z + b.z, c3 = a.w + b.w;
    float s = c0 + c1 + c2 + c3;
    float sq = c0*c0 + c1*c1 + c2*c2 + c3*c3;
    for (int o = 32; o > 0; o >>= 1) { s += __shfl_xor(s, o); sq += __shfl_xor(sq, o); }
    __shared__ float red[8];
    __shared__ float stats[2];
    const int wid = tid >> 6, lane = tid & 63;
    if (lane == 0) { red[wid] = s; red[4 + wid] = sq; }
    __syncthreads();
    if (tid == 0) {
        float S = red[0] + red[1] + red[2] + red[3];
        float Q = red[4] + red[5] + red[6] + red[7];
        float mu = S / (float)HDIM;
        float var = Q / (float)HDIM - mu * mu;
        stats[0] = mu; stats[1] = rsqrtf(var + 1e-5f);
    }
    __syncthreads();
    const float mu = stats[0], rstd = stats[1];
    const float4 w4 = *(const float4*)(ow + tid * 4);
    const float4 b4 = *(const float4*)(ob + tid * 4);
    float4 o;
    o.x = (c0 - mu) * rstd * w4.x + b4.x;
    o.y = (c1 - mu) * rstd * w4.y + b4.y;
    o.z = (c2 - mu) * rstd * w4.z + b4.z;
    o.w = (c3 - mu) * rstd * w4.w + b4.w;
    *(float4*)(out + (size_t)t * HDIM + tid * 4) = o;
}

extern "C" void kernel_launch(void* const* d_in, const int* in_sizes, int n_in,
                              void* d_out, int out_size, void* d_ws, size_t ws_size,
                              hipStream_t stream) {
    const float* x   = (const float*)d_in[0];
    const float* rlw = (const float*)d_in[1];
    const float* rlb = (const float*)d_in[2];
    const float* rw  = (const float*)d_in[3];
    const float* rb  = (const float*)d_in[4];
    const float* elw = (const float*)d_in[5];
    const float* elb = (const float*)d_in[6];
    const float* w1  = (const float*)d_in[7];
    const float* b1  = (const float*)d_in[8];
    const float* w2  = (const float*)d_in[9];
    const float* b2  = (const float*)d_in[10];
    const float* ow  = (const float*)d_in[11];
    const float* ob  = (const float*)d_in[12];
    float* out = (float*)d_out;

    char* ws = (char*)d_ws;
    // layout: xhat bf16 [T,H] | h bf16 [8192,I] | eo fp32 [T,2,H] | lists | counts | offs
    unsigned short* xhat = (unsigned short*)(ws);                       // 8,388,608 B
    unsigned short* hbuf = (unsigned short*)(ws + 8388608);             // 67,108,864 B
    float* eo            = (float*)(ws + 75497472);                     // 33,554,432 B
    int* ltok            = (int*)(ws + 109051904);                      // 131,072 B
    float* lwt           = (float*)(ws + 109051904 + 131072);           // 131,072 B
    int* counts          = (int*)(ws + 109051904 + 262144);             // 32 B
    int* offs            = (int*)(ws + 109051904 + 262144 + 32);        // 36 B

    hipMemsetAsync(counts, 0, 8 * sizeof(int), stream);
    k_ln_router<<<dim3(T_TOK), dim3(256), 0, stream>>>(x, rlw, rlb, rw, rb, xhat, counts, ltok, lwt);
    k_offs<<<dim3(1), dim3(64), 0, stream>>>(counts, offs);
    k_gemm1<<<dim3(32, 32, 8), dim3(256), 0, stream>>>(xhat, elw, elb, w1, b1, counts, offs, ltok, hbuf);
    k_gemm2<<<dim3(32, 8, 8), dim3(256), 0, stream>>>(hbuf, w2, b2, counts, offs, ltok, lwt, eo);
    k_final<<<dim3(T_TOK), dim3(256), 0, stream>>>(eo, ow, ob, out);
}

// Round 2
// 1443.548 us; speedup vs baseline: 1.9553x; 1.9553x over previous
//
#include <hip/hip_runtime.h>
#include <hip/hip_bf16.h>

#define T_TOK 4096
#define HDIM 1024
#define IDIM 4096
#define NEXP 8

typedef __bf16 bf16x8 __attribute__((ext_vector_type(8)));
typedef float f32x4 __attribute__((ext_vector_type(4)));
typedef unsigned short us8 __attribute__((ext_vector_type(8)));

__device__ __forceinline__ unsigned short f2bf(float f) {
    union { float f; unsigned int u; } v; v.f = f;
    unsigned int u = v.u;
    unsigned int r = u + 0x7fffu + ((u >> 16) & 1u);
    return (unsigned short)(r >> 16);
}
__device__ __forceinline__ float bf2f(unsigned short b) {
    union { unsigned int u; float f; } v; v.u = ((unsigned int)b) << 16;
    return v.f;
}

// ---------------- transpose+convert: src [E][R][C] f32 -> dst [E][C][R] bf16 ----------------
__global__ __launch_bounds__(256) void k_cvt_t(const float* __restrict__ src,
                                               unsigned short* __restrict__ dst,
                                               int R, int C) {
    __shared__ unsigned short tl[64][72];
    const int e = blockIdx.z;
    const int c0 = blockIdx.x * 64, r0 = blockIdx.y * 64;
    const int tid = threadIdx.x;
    #pragma unroll
    for (int it = 0; it < 4; it++) {
        int idx = it * 256 + tid;
        int rl = idx >> 4, cl = (idx & 15) * 4;
        float4 v = *(const float4*)(src + ((size_t)e * R + r0 + rl) * C + c0 + cl);
        tl[cl + 0][rl] = f2bf(v.x);
        tl[cl + 1][rl] = f2bf(v.y);
        tl[cl + 2][rl] = f2bf(v.z);
        tl[cl + 3][rl] = f2bf(v.w);
    }
    __syncthreads();
    #pragma unroll
    for (int it = 0; it < 2; it++) {
        int idx = it * 256 + tid;
        int cl = idx >> 3, ch = idx & 7;
        us8 v;
        __builtin_memcpy(&v, &tl[cl][ch * 8], 16);
        *(us8*)(dst + ((size_t)e * C + c0 + cl) * R + r0 + ch * 8) = v;
    }
}

// ---------------- LN stats + router top-2 + routing lists ----------------
__global__ __launch_bounds__(256) void k_ln_router(
    const float* __restrict__ x, const float* __restrict__ rlw, const float* __restrict__ rlb,
    const float* __restrict__ rw, const float* __restrict__ rb,
    unsigned short* __restrict__ xhat, int* __restrict__ counts,
    int* __restrict__ ltok, float* __restrict__ lwt)
{
    const int t = blockIdx.x, tid = threadIdx.x;
    const float4 v = *(const float4*)(x + (size_t)t * HDIM + tid * 4);
    float s  = v.x + v.y + v.z + v.w;
    float sq = v.x*v.x + v.y*v.y + v.z*v.z + v.w*v.w;
    for (int o = 32; o > 0; o >>= 1) { s += __shfl_xor(s, o); sq += __shfl_xor(sq, o); }
    __shared__ float red[8];
    __shared__ float stats[2];
    const int wid = tid >> 6, lane = tid & 63;
    if (lane == 0) { red[wid] = s; red[4 + wid] = sq; }
    __syncthreads();
    if (tid == 0) {
        float S = red[0] + red[1] + red[2] + red[3];
        float Q = red[4] + red[5] + red[6] + red[7];
        float mu = S / (float)HDIM;
        float var = Q / (float)HDIM - mu * mu;
        stats[0] = mu; stats[1] = rsqrtf(var + 1e-5f);
    }
    __syncthreads();
    const float mu = stats[0], rstd = stats[1];
    float xh[4];
    xh[0] = (v.x - mu) * rstd; xh[1] = (v.y - mu) * rstd;
    xh[2] = (v.z - mu) * rstd; xh[3] = (v.w - mu) * rstd;
    ushort4 o4;
    o4.x = f2bf(xh[0]); o4.y = f2bf(xh[1]); o4.z = f2bf(xh[2]); o4.w = f2bf(xh[3]);
    *(ushort4*)(xhat + (size_t)t * HDIM + tid * 4) = o4;

    float p[8];
    #pragma unroll
    for (int e = 0; e < 8; e++) p[e] = 0.f;
    const float4 w4 = *(const float4*)(rlw + tid * 4);
    const float4 b4 = *(const float4*)(rlb + tid * 4);
    const float wl[4] = { w4.x, w4.y, w4.z, w4.w };
    const float bl[4] = { b4.x, b4.y, b4.z, b4.w };
    #pragma unroll
    for (int j = 0; j < 4; j++) {
        float rl = xh[j] * wl[j] + bl[j];
        const float* wr = rw + (size_t)(tid * 4 + j) * 8;
        float4 wa = *(const float4*)(wr);
        float4 wb = *(const float4*)(wr + 4);
        p[0] += rl * wa.x; p[1] += rl * wa.y; p[2] += rl * wa.z; p[3] += rl * wa.w;
        p[4] += rl * wb.x; p[5] += rl * wb.y; p[6] += rl * wb.z; p[7] += rl * wb.w;
    }
    #pragma unroll
    for (int e = 0; e < 8; e++)
        for (int o = 32; o > 0; o >>= 1) p[e] += __shfl_xor(p[e], o);
    __shared__ float pw[4][8];
    if (lane == 0) {
        #pragma unroll
        for (int e = 0; e < 8; e++) pw[wid][e] = p[e];
    }
    __syncthreads();
    if (tid == 0) {
        float lg[8];
        #pragma unroll
        for (int e = 0; e < 8; e++)
            lg[e] = pw[0][e] + pw[1][e] + pw[2][e] + pw[3][e] + rb[e];
        int i0 = 0;
        #pragma unroll
        for (int e = 1; e < 8; e++) if (lg[e] > lg[i0]) i0 = e;
        int i1 = (i0 == 0) ? 1 : 0;
        #pragma unroll
        for (int e = 0; e < 8; e++) if (e != i0 && lg[e] > lg[i1]) i1 = e;
        float e1 = expf(lg[i1] - lg[i0]);
        float w0 = 1.f / (1.f + e1);
        float w1 = 1.f - w0;
        int p0 = atomicAdd(&counts[i0], 1);
        ltok[i0 * T_TOK + p0] = t * 2 + 0; lwt[i0 * T_TOK + p0] = w0;
        int p1 = atomicAdd(&counts[i1], 1);
        ltok[i1 * T_TOK + p1] = t * 2 + 1; lwt[i1 * T_TOK + p1] = w1;
    }
}

// ---------------- tiny prefix sum ----------------
__global__ void k_offs(const int* __restrict__ counts, int* __restrict__ offs) {
    if (threadIdx.x == 0 && blockIdx.x == 0) {
        int a = 0;
        for (int e = 0; e < NEXP; e++) { offs[e] = a; a += counts[e]; }
        offs[NEXP] = a;
    }
}

// ---------------- build packed, expert-LN-affined A (bf16) ----------------
__global__ __launch_bounds__(256) void k_ag_build(
    const unsigned short* __restrict__ xhat, const float* __restrict__ elw, const float* __restrict__ elb,
    const int* __restrict__ counts, const int* __restrict__ offs, const int* __restrict__ ltok,
    unsigned short* __restrict__ ag)
{
    const int e = blockIdx.z, rt = blockIdx.x, cc = blockIdx.y;
    const int ne = counts[e];
    if (rt * 128 >= ne) return;
    const int off = offs[e];
    const int tid = threadIdx.x;
    const int row = rt * 128 + (tid >> 1);
    if (row >= ne) return;
    const int tok = ltok[e * T_TOK + row] >> 1;
    const int cb = cc * 256 + (tid & 1) * 128;
    const unsigned short* src = xhat + (size_t)tok * HDIM + cb;
    unsigned short* dst = ag + (size_t)(off + row) * HDIM + cb;
    const float* wv = elw + (size_t)e * HDIM + cb;
    const float* bv = elb + (size_t)e * HDIM + cb;
    #pragma unroll
    for (int j = 0; j < 128; j += 8) {
        us8 xv = *(const us8*)(src + j);
        us8 o;
        #pragma unroll
        for (int q = 0; q < 8; q++)
            o[q] = f2bf(bf2f(xv[q]) * wv[j + q] + bv[j + q]);
        *(us8*)(dst + j) = o;
    }
}

// ---------------- GEMM1: Ag @ w1bf^T(-packed) -> +b1 -> gelu -> hbuf (bf16) ----------------
__global__ __launch_bounds__(256) void k_gemm1(
    const unsigned short* __restrict__ ag, const unsigned short* __restrict__ wbf,
    const float* __restrict__ b1,
    const int* __restrict__ counts, const int* __restrict__ offs,
    unsigned short* __restrict__ hbuf)
{
    const int e = blockIdx.z, rt = blockIdx.x, ct = blockIdx.y;
    const int ne = counts[e];
    if (rt * 128 >= ne) return;
    const int off = offs[e];
    __shared__ unsigned short As[128][80];
    __shared__ unsigned short Bs[128][80];
    const int tid = threadIdx.x;
    const int srow = tid >> 1, sh = (tid & 1) * 32;
    const unsigned short* aptr = ag + (size_t)(off + rt * 128 + srow) * HDIM + sh;
    const unsigned short* bptr = wbf + (size_t)e * IDIM * HDIM + (size_t)(ct * 128 + srow) * HDIM + sh;

    f32x4 acc[4][4];
    #pragma unroll
    for (int i = 0; i < 4; i++)
        #pragma unroll
        for (int j = 0; j < 4; j++) acc[i][j] = (f32x4){0.f, 0.f, 0.f, 0.f};

    const int wid = tid >> 6, lane = tid & 63;
    const int wm = (wid & 1) * 64, wn = (wid >> 1) * 64;
    const int fr = lane & 15, quad = lane >> 4;

    us8 ra[4], rb[4];
    #pragma unroll
    for (int j = 0; j < 4; j++) {
        ra[j] = *(const us8*)(aptr + j * 8);
        rb[j] = *(const us8*)(bptr + j * 8);
    }
    for (int k0 = 0; k0 < HDIM; k0 += 64) {
        #pragma unroll
        for (int j = 0; j < 4; j++) {
            *(us8*)&As[srow][sh + j * 8] = ra[j];
            *(us8*)&Bs[srow][sh + j * 8] = rb[j];
        }
        __syncthreads();
        if (k0 + 64 < HDIM) {
            #pragma unroll
            for (int j = 0; j < 4; j++) {
                ra[j] = *(const us8*)(aptr + k0 + 64 + j * 8);
                rb[j] = *(const us8*)(bptr + k0 + 64 + j * 8);
            }
        }
        #pragma unroll
        for (int ks = 0; ks < 64; ks += 32) {
            bf16x8 af[4], bfr[4];
            #pragma unroll
            for (int i = 0; i < 4; i++)
                __builtin_memcpy(&af[i], &As[wm + i * 16 + fr][ks + quad * 8], 16);
            #pragma unroll
            for (int j = 0; j < 4; j++)
                __builtin_memcpy(&bfr[j], &Bs[wn + j * 16 + fr][ks + quad * 8], 16);
            #pragma unroll
            for (int i = 0; i < 4; i++)
                #pragma unroll
                for (int j = 0; j < 4; j++)
                    acc[i][j] = __builtin_amdgcn_mfma_f32_16x16x32_bf16(af[i], bfr[j], acc[i][j], 0, 0, 0);
        }
        __syncthreads();
    }
    #pragma unroll
    for (int j = 0; j < 4; j++) {
        const int n = ct * 128 + wn + j * 16 + fr;
        const float bias = b1[e * IDIM + n];
        #pragma unroll
        for (int i = 0; i < 4; i++) {
            const int mbase = rt * 128 + wm + i * 16 + quad * 4;
            #pragma unroll
            for (int rg = 0; rg < 4; rg++) {
                const int r = mbase + rg;
                if (r < ne) {
                    float v = acc[i][j][rg] + bias;
                    float g = 0.5f * v * (1.f + erff(v * 0.70710678118654752f));
                    hbuf[(size_t)(off + r) * IDIM + n] = f2bf(g);
                }
            }
        }
    }
}

// ---------------- GEMM2: hbuf @ w2bf -> +b2 -> *wt -> eo[t,slot,:] ----------------
__global__ __launch_bounds__(256) void k_gemm2(
    const unsigned short* __restrict__ hbuf, const unsigned short* __restrict__ wbf,
    const float* __restrict__ b2,
    const int* __restrict__ counts, const int* __restrict__ offs,
    const int* __restrict__ ltok, const float* __restrict__ lwt,
    float* __restrict__ eo)
{
    const int e = blockIdx.z, rt = blockIdx.x, ct = blockIdx.y;
    const int ne = counts[e];
    if (rt * 128 >= ne) return;
    const int off = offs[e];
    __shared__ unsigned short As[128][80];
    __shared__ unsigned short Bs[128][80];
    __shared__ int dst[128];
    __shared__ float wts[128];
    const int tid = threadIdx.x;
    if (tid < 128) {
        int r = rt * 128 + tid;
        if (r < ne) { dst[tid] = ltok[e * T_TOK + r]; wts[tid] = lwt[e * T_TOK + r]; }
        else { dst[tid] = -1; wts[tid] = 0.f; }
    }
    const int srow = tid >> 1, sh = (tid & 1) * 32;
    const unsigned short* aptr = hbuf + (size_t)(off + rt * 128 + srow) * IDIM + sh;
    const unsigned short* bptr = wbf + (size_t)e * HDIM * IDIM + (size_t)(ct * 128 + srow) * IDIM + sh;

    f32x4 acc[4][4];
    #pragma unroll
    for (int i = 0; i < 4; i++)
        #pragma unroll
        for (int j = 0; j < 4; j++) acc[i][j] = (f32x4){0.f, 0.f, 0.f, 0.f};

    const int wid = tid >> 6, lane = tid & 63;
    const int wm = (wid & 1) * 64, wn = (wid >> 1) * 64;
    const int fr = lane & 15, quad = lane >> 4;

    us8 ra[4], rb[4];
    #pragma unroll
    for (int j = 0; j < 4; j++) {
        ra[j] = *(const us8*)(aptr + j * 8);
        rb[j] = *(const us8*)(bptr + j * 8);
    }
    for (int k0 = 0; k0 < IDIM; k0 += 64) {
        #pragma unroll
        for (int j = 0; j < 4; j++) {
            *(us8*)&As[srow][sh + j * 8] = ra[j];
            *(us8*)&Bs[srow][sh + j * 8] = rb[j];
        }
        __syncthreads();
        if (k0 + 64 < IDIM) {
            #pragma unroll
            for (int j = 0; j < 4; j++) {
                ra[j] = *(const us8*)(aptr + k0 + 64 + j * 8);
                rb[j] = *(const us8*)(bptr + k0 + 64 + j * 8);
            }
        }
        #pragma unroll
        for (int ks = 0; ks < 64; ks += 32) {
            bf16x8 af[4], bfr[4];
            #pragma unroll
            for (int i = 0; i < 4; i++)
                __builtin_memcpy(&af[i], &As[wm + i * 16 + fr][ks + quad * 8], 16);
            #pragma unroll
            for (int j = 0; j < 4; j++)
                __builtin_memcpy(&bfr[j], &Bs[wn + j * 16 + fr][ks + quad * 8], 16);
            #pragma unroll
            for (int i = 0; i < 4; i++)
                #pragma unroll
                for (int j = 0; j < 4; j++)
                    acc[i][j] = __builtin_amdgcn_mfma_f32_16x16x32_bf16(af[i], bfr[j], acc[i][j], 0, 0, 0);
        }
        __syncthreads();
    }
    #pragma unroll
    for (int j = 0; j < 4; j++) {
        const int n = ct * 128 + wn + j * 16 + fr;
        const float bias = b2[e * HDIM + n];
        #pragma unroll
        for (int i = 0; i < 4; i++) {
            const int mbase = wm + i * 16 + quad * 4;
            #pragma unroll
            for (int rg = 0; rg < 4; rg++) {
                const int m = mbase + rg;
                const int d = dst[m];
                if (d >= 0) {
                    float v = (acc[i][j][rg] + bias) * wts[m];
                    eo[(size_t)d * HDIM + n] = v;
                }
            }
        }
    }
}

// ---------------- combine + final LN ----------------
__global__ __launch_bounds__(256) void k_final(
    const float* __restrict__ eo, const float* __restrict__ ow, const float* __restrict__ ob,
    float* __restrict__ out)
{
    const int t = blockIdx.x, tid = threadIdx.x;
    const float4 a = *(const float4*)(eo + (size_t)(t * 2 + 0) * HDIM + tid * 4);
    const float4 b = *(const float4*)(eo + (size_t)(t * 2 + 1) * HDIM + tid * 4);
    float c0 = a.x + b.x, c1 = a.y + b.y, c2 = a.z + b.z, c3 = a.w + b.w;
    float s = c0 + c1 + c2 + c3;
    float sq = c0*c0 + c1*c1 + c2*c2 + c3*c3;
    for (int o = 32; o > 0; o >>= 1) { s += __shfl_xor(s, o); sq += __shfl_xor(sq, o); }
    __shared__ float red[8];
    __shared__ float stats[2];
    const int wid = tid >> 6, lane = tid & 63;
    if (lane == 0) { red[wid] = s; red[4 + wid] = sq; }
    __syncthreads();
    if (tid == 0) {
        float S = red[0] + red[1] + red[2] + red[3];
        float Q = red[4] + red[5] + red[6] + red[7];
        float mu = S / (float)HDIM;
        float var = Q / (float)HDIM - mu * mu;
        stats[0] = mu; stats[1] = rsqrtf(var + 1e-5f);
    }
    __syncthreads();
    const float mu = stats[0], rstd = stats[1];
    const float4 w4 = *(const float4*)(ow + tid * 4);
    const float4 b4 = *(const float4*)(ob + tid * 4);
    float4 o;
    o.x = (c0 - mu) * rstd * w4.x + b4.x;
    o.y = (c1 - mu) * rstd * w4.y + b4.y;
    o.z = (c2 - mu) * rstd * w4.z + b4.z;
    o.w = (c3 - mu) * rstd * w4.w + b4.w;
    *(float4*)(out + (size_t)t * HDIM + tid * 4) = o;
}

extern "C" void kernel_launch(void* const* d_in, const int* in_sizes, int n_in,
                              void* d_out, int out_size, void* d_ws, size_t ws_size,
                              hipStream_t stream) {
    const float* x   = (const float*)d_in[0];
    const float* rlw = (const float*)d_in[1];
    const float* rlb = (const float*)d_in[2];
    const float* rw  = (const float*)d_in[3];
    const float* rb  = (const float*)d_in[4];
    const float* elw = (const float*)d_in[5];
    const float* elb = (const float*)d_in[6];
    const float* w1  = (const float*)d_in[7];
    const float* b1  = (const float*)d_in[8];
    const float* w2  = (const float*)d_in[9];
    const float* b2  = (const float*)d_in[10];
    const float* ow  = (const float*)d_in[11];
    const float* ob  = (const float*)d_in[12];
    float* out = (float*)d_out;

    char* ws = (char*)d_ws;
    // layout (~160.3 MB):
    //   [0, 64MB):    wbf  — w1 bf16 [E][I][H] for GEMM1, then overwritten with w2 bf16 [E][H][I] for GEMM2
    //   [64, 128MB):  hbuf bf16 [8192][IDIM]; xhat bf16 [T][H] (8MB) lives at its base until GEMM1 runs
    //   [128MB, +32MB): Ag bf16 [8320][H] (17MB, dead after GEMM1) overlapped by eo fp32 [T][2][H] (32MB)
    //   then: ltok[8][T], lwt[8][T], counts[8], offs[9]
    const size_t MB = 1024 * 1024;
    unsigned short* wbf  = (unsigned short*)(ws);
    unsigned short* hbuf = (unsigned short*)(ws + 64 * MB);
    unsigned short* xhat = (unsigned short*)(ws + 64 * MB);
    unsigned short* ag   = (unsigned short*)(ws + 128 * MB);
    float* eo            = (float*)(ws + 128 * MB);
    char* tail           = ws + 160 * MB;
    int* ltok            = (int*)(tail);
    float* lwt           = (float*)(tail + 131072);
    int* counts          = (int*)(tail + 262144);
    int* offs            = (int*)(tail + 262144 + 64);

    hipMemsetAsync(counts, 0, 8 * sizeof(int), stream);
    // w1 [E][H][I] -> wbf [E][I][H] bf16
    k_cvt_t<<<dim3(IDIM / 64, HDIM / 64, NEXP), dim3(256), 0, stream>>>(w1, wbf, HDIM, IDIM);
    k_ln_router<<<dim3(T_TOK), dim3(256), 0, stream>>>(x, rlw, rlb, rw, rb, xhat, counts, ltok, lwt);
    k_offs<<<dim3(1), dim3(64), 0, stream>>>(counts, offs);
    k_ag_build<<<dim3(32, 4, NEXP), dim3(256), 0, stream>>>(xhat, elw, elb, counts, offs, ltok, ag);
    k_gemm1<<<dim3(32, 32, NEXP), dim3(256), 0, stream>>>(ag, wbf, b1, counts, offs, hbuf);
    // w2 [E][I][H] -> wbf [E][H][I] bf16 (reuses buffer; Ag region becomes eo)
    k_cvt_t<<<dim3(HDIM / 64, IDIM / 64, NEXP), dim3(256), 0, stream>>>(w2, wbf, IDIM, HDIM);
    k_gemm2<<<dim3(32, 8, NEXP), dim3(256), 0, stream>>>(hbuf, wbf, b2, counts, offs, ltok, lwt, eo);
    k_final<<<dim3(T_TOK), dim3(256), 0, stream>>>(eo, ow, ob, out);
}

// Round 3
// 1280.933 us; speedup vs baseline: 2.2035x; 1.1270x over previous
//
#include <hip/hip_runtime.h>
#include <hip/hip_bf16.h>

#define T_TOK 4096
#define HDIM 1024
#define IDIM 4096
#define NEXP 8

typedef __bf16 bf16x8 __attribute__((ext_vector_type(8)));
typedef float f32x4 __attribute__((ext_vector_type(4)));
typedef unsigned short us8 __attribute__((ext_vector_type(8)));

__device__ __forceinline__ unsigned short f2bf(float f) {
    union { float f; unsigned int u; } v; v.f = f;
    unsigned int u = v.u;
    unsigned int r = u + 0x7fffu + ((u >> 16) & 1u);
    return (unsigned short)(r >> 16);
}
__device__ __forceinline__ float bf2f(unsigned short b) {
    union { unsigned int u; float f; } v; v.u = ((unsigned int)b) << 16;
    return v.f;
}

// async 16B/lane global->LDS: wave-uniform lds base, lane l lands at base + l*16
__device__ __forceinline__ void gll16(const unsigned short* g, unsigned short* lds) {
    __builtin_amdgcn_global_load_lds(
        (const __attribute__((address_space(1))) unsigned int*)g,
        (__attribute__((address_space(3))) unsigned int*)lds, 16, 0, 0);
}

// ---------------- transpose+convert: src [E][R][C] f32 -> dst [E][C][R] bf16 ----------------
__global__ __launch_bounds__(256) void k_cvt_t(const float* __restrict__ src,
                                               unsigned short* __restrict__ dst,
                                               int R, int C) {
    __shared__ unsigned short tl[64][72];
    const int e = blockIdx.z;
    const int c0 = blockIdx.x * 64, r0 = blockIdx.y * 64;
    const int tid = threadIdx.x;
    #pragma unroll
    for (int it = 0; it < 4; it++) {
        int idx = it * 256 + tid;
        int rl = idx >> 4, cl = (idx & 15) * 4;
        float4 v = *(const float4*)(src + ((size_t)e * R + r0 + rl) * C + c0 + cl);
        tl[cl + 0][rl] = f2bf(v.x);
        tl[cl + 1][rl] = f2bf(v.y);
        tl[cl + 2][rl] = f2bf(v.z);
        tl[cl + 3][rl] = f2bf(v.w);
    }
    __syncthreads();
    #pragma unroll
    for (int it = 0; it < 2; it++) {
        int idx = it * 256 + tid;
        int cl = idx >> 3, ch = idx & 7;
        us8 v;
        __builtin_memcpy(&v, &tl[cl][ch * 8], 16);
        *(us8*)(dst + ((size_t)e * C + c0 + cl) * R + r0 + ch * 8) = v;
    }
}

// ---------------- LN stats + router top-2 + routing lists ----------------
__global__ __launch_bounds__(256) void k_ln_router(
    const float* __restrict__ x, const float* __restrict__ rlw, const float* __restrict__ rlb,
    const float* __restrict__ rw, const float* __restrict__ rb,
    unsigned short* __restrict__ xhat, int* __restrict__ counts,
    int* __restrict__ ltok, float* __restrict__ lwt)
{
    const int t = blockIdx.x, tid = threadIdx.x;
    const float4 v = *(const float4*)(x + (size_t)t * HDIM + tid * 4);
    float s  = v.x + v.y + v.z + v.w;
    float sq = v.x*v.x + v.y*v.y + v.z*v.z + v.w*v.w;
    for (int o = 32; o > 0; o >>= 1) { s += __shfl_xor(s, o); sq += __shfl_xor(sq, o); }
    __shared__ float red[8];
    __shared__ float stats[2];
    const int wid = tid >> 6, lane = tid & 63;
    if (lane == 0) { red[wid] = s; red[4 + wid] = sq; }
    __syncthreads();
    if (tid == 0) {
        float S = red[0] + red[1] + red[2] + red[3];
        float Q = red[4] + red[5] + red[6] + red[7];
        float mu = S / (float)HDIM;
        float var = Q / (float)HDIM - mu * mu;
        stats[0] = mu; stats[1] = rsqrtf(var + 1e-5f);
    }
    __syncthreads();
    const float mu = stats[0], rstd = stats[1];
    float xh[4];
    xh[0] = (v.x - mu) * rstd; xh[1] = (v.y - mu) * rstd;
    xh[2] = (v.z - mu) * rstd; xh[3] = (v.w - mu) * rstd;
    ushort4 o4;
    o4.x = f2bf(xh[0]); o4.y = f2bf(xh[1]); o4.z = f2bf(xh[2]); o4.w = f2bf(xh[3]);
    *(ushort4*)(xhat + (size_t)t * HDIM + tid * 4) = o4;

    float p[8];
    #pragma unroll
    for (int e = 0; e < 8; e++) p[e] = 0.f;
    const float4 w4 = *(const float4*)(rlw + tid * 4);
    const float4 b4 = *(const float4*)(rlb + tid * 4);
    const float wl[4] = { w4.x, w4.y, w4.z, w4.w };
    const float bl[4] = { b4.x, b4.y, b4.z, b4.w };
    #pragma unroll
    for (int j = 0; j < 4; j++) {
        float rl = xh[j] * wl[j] + bl[j];
        const float* wr = rw + (size_t)(tid * 4 + j) * 8;
        float4 wa = *(const float4*)(wr);
        float4 wb = *(const float4*)(wr + 4);
        p[0] += rl * wa.x; p[1] += rl * wa.y; p[2] += rl * wa.z; p[3] += rl * wa.w;
        p[4] += rl * wb.x; p[5] += rl * wb.y; p[6] += rl * wb.z; p[7] += rl * wb.w;
    }
    #pragma unroll
    for (int e = 0; e < 8; e++)
        for (int o = 32; o > 0; o >>= 1) p[e] += __shfl_xor(p[e], o);
    __shared__ float pw[4][8];
    if (lane == 0) {
        #pragma unroll
        for (int e = 0; e < 8; e++) pw[wid][e] = p[e];
    }
    __syncthreads();
    if (tid == 0) {
        float lg[8];
        #pragma unroll
        for (int e = 0; e < 8; e++)
            lg[e] = pw[0][e] + pw[1][e] + pw[2][e] + pw[3][e] + rb[e];
        int i0 = 0;
        #pragma unroll
        for (int e = 1; e < 8; e++) if (lg[e] > lg[i0]) i0 = e;
        int i1 = (i0 == 0) ? 1 : 0;
        #pragma unroll
        for (int e = 0; e < 8; e++) if (e != i0 && lg[e] > lg[i1]) i1 = e;
        float e1 = expf(lg[i1] - lg[i0]);
        float w0 = 1.f / (1.f + e1);
        float w1 = 1.f - w0;
        int p0 = atomicAdd(&counts[i0], 1);
        ltok[i0 * T_TOK + p0] = t * 2 + 0; lwt[i0 * T_TOK + p0] = w0;
        int p1 = atomicAdd(&counts[i1], 1);
        ltok[i1 * T_TOK + p1] = t * 2 + 1; lwt[i1 * T_TOK + p1] = w1;
    }
}

// ---------------- tiny prefix sum ----------------
__global__ void k_offs(const int* __restrict__ counts, int* __restrict__ offs) {
    if (threadIdx.x == 0 && blockIdx.x == 0) {
        int a = 0;
        for (int e = 0; e < NEXP; e++) { offs[e] = a; a += counts[e]; }
        offs[NEXP] = a;
    }
}

// ---------------- build packed, expert-LN-affined A (bf16) ----------------
__global__ __launch_bounds__(256) void k_ag_build(
    const unsigned short* __restrict__ xhat, const float* __restrict__ elw, const float* __restrict__ elb,
    const int* __restrict__ counts, const int* __restrict__ offs, const int* __restrict__ ltok,
    unsigned short* __restrict__ ag)
{
    const int e = blockIdx.z, rt = blockIdx.x, cc = blockIdx.y;
    const int ne = counts[e];
    if (rt * 128 >= ne) return;
    const int off = offs[e];
    const int tid = threadIdx.x;
    const int row = rt * 128 + (tid >> 1);
    if (row >= ne) return;
    const int tok = ltok[e * T_TOK + row] >> 1;
    const int cb = cc * 256 + (tid & 1) * 128;
    const unsigned short* src = xhat + (size_t)tok * HDIM + cb;
    unsigned short* dst = ag + (size_t)(off + row) * HDIM + cb;
    const float* wv = elw + (size_t)e * HDIM + cb;
    const float* bv = elb + (size_t)e * HDIM + cb;
    #pragma unroll
    for (int j = 0; j < 128; j += 8) {
        us8 xv = *(const us8*)(src + j);
        us8 o;
        #pragma unroll
        for (int q = 0; q < 8; q++)
            o[q] = f2bf(bf2f(xv[q]) * wv[j + q] + bv[j + q]);
        *(us8*)(dst + j) = o;
    }
}

// ---------------- GEMM1: Ag @ w1bf^T -> +b1 -> gelu -> hbuf (bf16) ----------------
// m97 structure: unpadded LDS, global_load_lds width=16, 2-barrier K-loop.
__global__ __launch_bounds__(256) void k_gemm1(
    const unsigned short* __restrict__ ag, const unsigned short* __restrict__ wbf,
    const float* __restrict__ b1,
    const int* __restrict__ counts, const int* __restrict__ offs,
    unsigned short* __restrict__ hbuf)
{
    const int e = blockIdx.z, rt = blockIdx.x, ct = blockIdx.y;
    const int ne = counts[e];
    if (rt * 128 >= ne) return;
    const int off = offs[e];
    __shared__ unsigned short As[128 * 64];
    __shared__ unsigned short Bs[128 * 64];
    const int tid = threadIdx.x;
    const int wid = tid >> 6, lane = tid & 63;

    // staging: wave wid covers rows 32*wid..+31; inst i covers 8 rows; lane l -> row +(l>>3), col (l&7)*8
    const unsigned short* ga = ag + (size_t)(off + rt * 128 + 32 * wid + (lane >> 3)) * HDIM + (lane & 7) * 8;
    const unsigned short* gb = wbf + (size_t)e * IDIM * HDIM
                             + (size_t)(ct * 128 + 32 * wid + (lane >> 3)) * HDIM + (lane & 7) * 8;
    unsigned short* lA = As + wid * 2048;
    unsigned short* lB = Bs + wid * 2048;

    f32x4 acc[4][4];
    #pragma unroll
    for (int i = 0; i < 4; i++)
        #pragma unroll
        for (int j = 0; j < 4; j++) acc[i][j] = (f32x4){0.f, 0.f, 0.f, 0.f};

    const int wm = (wid & 1) * 64, wn = (wid >> 1) * 64;
    const int fr = lane & 15, quad = lane >> 4;

    for (int k0 = 0; k0 < HDIM; k0 += 64) {
        #pragma unroll
        for (int i = 0; i < 4; i++) {
            gll16(ga + (size_t)(8 * i) * HDIM + k0, lA + i * 512);
            gll16(gb + (size_t)(8 * i) * HDIM + k0, lB + i * 512);
        }
        __builtin_amdgcn_s_waitcnt(0x0f70);  // vmcnt(0)
        __syncthreads();
        #pragma unroll
        for (int ks = 0; ks < 64; ks += 32) {
            bf16x8 af[4], bfr[4];
            #pragma unroll
            for (int i = 0; i < 4; i++)
                __builtin_memcpy(&af[i], As + (wm + i * 16 + fr) * 64 + ks + quad * 8, 16);
            #pragma unroll
            for (int j = 0; j < 4; j++)
                __builtin_memcpy(&bfr[j], Bs + (wn + j * 16 + fr) * 64 + ks + quad * 8, 16);
            #pragma unroll
            for (int i = 0; i < 4; i++)
                #pragma unroll
                for (int j = 0; j < 4; j++)
                    acc[i][j] = __builtin_amdgcn_mfma_f32_16x16x32_bf16(af[i], bfr[j], acc[i][j], 0, 0, 0);
        }
        __syncthreads();
    }
    #pragma unroll
    for (int j = 0; j < 4; j++) {
        const int n = ct * 128 + wn + j * 16 + fr;
        const float bias = b1[e * IDIM + n];
        #pragma unroll
        for (int i = 0; i < 4; i++) {
            const int mbase = rt * 128 + wm + i * 16 + quad * 4;
            #pragma unroll
            for (int rg = 0; rg < 4; rg++) {
                const int r = mbase + rg;
                if (r < ne) {
                    float v = acc[i][j][rg] + bias;
                    float g = 0.5f * v * (1.f + erff(v * 0.70710678118654752f));
                    hbuf[(size_t)(off + r) * IDIM + n] = f2bf(g);
                }
            }
        }
    }
}

// ---------------- GEMM2: hbuf @ w2bf -> +b2 -> *wt -> eo[t,slot,:] ----------------
__global__ __launch_bounds__(256) void k_gemm2(
    const unsigned short* __restrict__ hbuf, const unsigned short* __restrict__ wbf,
    const float* __restrict__ b2,
    const int* __restrict__ counts, const int* __restrict__ offs,
    const int* __restrict__ ltok, const float* __restrict__ lwt,
    float* __restrict__ eo)
{
    const int e = blockIdx.z, rt = blockIdx.x, ct = blockIdx.y;
    const int ne = counts[e];
    if (rt * 128 >= ne) return;
    const int off = offs[e];
    __shared__ unsigned short As[128 * 64];
    __shared__ unsigned short Bs[128 * 64];
    __shared__ int dst[128];
    __shared__ float wts[128];
    const int tid = threadIdx.x;
    if (tid < 128) {
        int r = rt * 128 + tid;
        if (r < ne) { dst[tid] = ltok[e * T_TOK + r]; wts[tid] = lwt[e * T_TOK + r]; }
        else { dst[tid] = -1; wts[tid] = 0.f; }
    }
    const int wid = tid >> 6, lane = tid & 63;
    const unsigned short* ga = hbuf + (size_t)(off + rt * 128 + 32 * wid + (lane >> 3)) * IDIM + (lane & 7) * 8;
    const unsigned short* gb = wbf + (size_t)e * HDIM * IDIM
                             + (size_t)(ct * 128 + 32 * wid + (lane >> 3)) * IDIM + (lane & 7) * 8;
    unsigned short* lA = As + wid * 2048;
    unsigned short* lB = Bs + wid * 2048;

    f32x4 acc[4][4];
    #pragma unroll
    for (int i = 0; i < 4; i++)
        #pragma unroll
        for (int j = 0; j < 4; j++) acc[i][j] = (f32x4){0.f, 0.f, 0.f, 0.f};

    const int wm = (wid & 1) * 64, wn = (wid >> 1) * 64;
    const int fr = lane & 15, quad = lane >> 4;

    for (int k0 = 0; k0 < IDIM; k0 += 64) {
        #pragma unroll
        for (int i = 0; i < 4; i++) {
            gll16(ga + (size_t)(8 * i) * IDIM + k0, lA + i * 512);
            gll16(gb + (size_t)(8 * i) * IDIM + k0, lB + i * 512);
        }
        __builtin_amdgcn_s_waitcnt(0x0f70);  // vmcnt(0)
        __syncthreads();
        #pragma unroll
        for (int ks = 0; ks < 64; ks += 32) {
            bf16x8 af[4], bfr[4];
            #pragma unroll
            for (int i = 0; i < 4; i++)
                __builtin_memcpy(&af[i], As + (wm + i * 16 + fr) * 64 + ks + quad * 8, 16);
            #pragma unroll
            for (int j = 0; j < 4; j++)
                __builtin_memcpy(&bfr[j], Bs + (wn + j * 16 + fr) * 64 + ks + quad * 8, 16);
            #pragma unroll
            for (int i = 0; i < 4; i++)
                #pragma unroll
                for (int j = 0; j < 4; j++)
                    acc[i][j] = __builtin_amdgcn_mfma_f32_16x16x32_bf16(af[i], bfr[j], acc[i][j], 0, 0, 0);
        }
        __syncthreads();
    }
    #pragma unroll
    for (int j = 0; j < 4; j++) {
        const int n = ct * 128 + wn + j * 16 + fr;
        const float bias = b2[e * HDIM + n];
        #pragma unroll
        for (int i = 0; i < 4; i++) {
            const int mbase = wm + i * 16 + quad * 4;
            #pragma unroll
            for (int rg = 0; rg < 4; rg++) {
                const int m = mbase + rg;
                const int d = dst[m];
                if (d >= 0) {
                    float v = (acc[i][j][rg] + bias) * wts[m];
                    eo[(size_t)d * HDIM + n] = v;
                }
            }
        }
    }
}

// ---------------- combine + final LN ----------------
__global__ __launch_bounds__(256) void k_final(
    const float* __restrict__ eo, const float* __restrict__ ow, const float* __restrict__ ob,
    float* __restrict__ out)
{
    const int t = blockIdx.x, tid = threadIdx.x;
    const float4 a = *(const float4*)(eo + (size_t)(t * 2 + 0) * HDIM + tid * 4);
    const float4 b = *(const float4*)(eo + (size_t)(t * 2 + 1) * HDIM + tid * 4);
    float c0 = a.x + b.x, c1 = a.y + b.y, c2 = a.z + b.z, c3 = a.w + b.w;
    float s = c0 + c1 + c2 + c3;
    float sq = c0*c0 + c1*c1 + c2*c2 + c3*c3;
    for (int o = 32; o > 0; o >>= 1) { s += __shfl_xor(s, o); sq += __shfl_xor(sq, o); }
    __shared__ float red[8];
    __shared__ float stats[2];
    const int wid = tid >> 6, lane = tid & 63;
    if (lane == 0) { red[wid] = s; red[4 + wid] = sq; }
    __syncthreads();
    if (tid == 0) {
        float S = red[0] + red[1] + red[2] + red[3];
        float Q = red[4] + red[5] + red[6] + red[7];
        float mu = S / (float)HDIM;
        float var = Q / (float)HDIM - mu * mu;
        stats[0] = mu; stats[1] = rsqrtf(var + 1e-5f);
    }
    __syncthreads();
    const float mu = stats[0], rstd = stats[1];
    const float4 w4 = *(const float4*)(ow + tid * 4);
    const float4 b4 = *(const float4*)(ob + tid * 4);
    float4 o;
    o.x = (c0 - mu) * rstd * w4.x + b4.x;
    o.y = (c1 - mu) * rstd * w4.y + b4.y;
    o.z = (c2 - mu) * rstd * w4.z + b4.z;
    o.w = (c3 - mu) * rstd * w4.w + b4.w;
    *(float4*)(out + (size_t)t * HDIM + tid * 4) = o;
}

extern "C" void kernel_launch(void* const* d_in, const int* in_sizes, int n_in,
                              void* d_out, int out_size, void* d_ws, size_t ws_size,
                              hipStream_t stream) {
    const float* x   = (const float*)d_in[0];
    const float* rlw = (const float*)d_in[1];
    const float* rlb = (const float*)d_in[2];
    const float* rw  = (const float*)d_in[3];
    const float* rb  = (const float*)d_in[4];
    const float* elw = (const float*)d_in[5];
    const float* elb = (const float*)d_in[6];
    const float* w1  = (const float*)d_in[7];
    const float* b1  = (const float*)d_in[8];
    const float* w2  = (const float*)d_in[9];
    const float* b2  = (const float*)d_in[10];
    const float* ow  = (const float*)d_in[11];
    const float* ob  = (const float*)d_in[12];
    float* out = (float*)d_out;

    char* ws = (char*)d_ws;
    // layout (~160.3 MB):
    //   [0, 64MB):    wbf  — w1 bf16 [E][I][H] for GEMM1, then overwritten with w2 bf16 [E][H][I] for GEMM2
    //   [64, 128MB):  hbuf bf16 [8192][IDIM]; xhat bf16 [T][H] (8MB) lives at its base until GEMM1 runs
    //   [128MB, +32MB): Ag bf16 [8320][H] (17MB, dead after GEMM1) overlapped by eo fp32 [T][2][H] (32MB)
    //   then: ltok[8][T], lwt[8][T], counts[8], offs[9]
    const size_t MB = 1024 * 1024;
    unsigned short* wbf  = (unsigned short*)(ws);
    unsigned short* hbuf = (unsigned short*)(ws + 64 * MB);
    unsigned short* xhat = (unsigned short*)(ws + 64 * MB);
    unsigned short* ag   = (unsigned short*)(ws + 128 * MB);
    float* eo            = (float*)(ws + 128 * MB);
    char* tail           = ws + 160 * MB;
    int* ltok            = (int*)(tail);
    float* lwt           = (float*)(tail + 131072);
    int* counts          = (int*)(tail + 262144);
    int* offs            = (int*)(tail + 262144 + 64);

    hipMemsetAsync(counts, 0, 8 * sizeof(int), stream);
    // w1 [E][H][I] -> wbf [E][I][H] bf16
    k_cvt_t<<<dim3(IDIM / 64, HDIM / 64, NEXP), dim3(256), 0, stream>>>(w1, wbf, HDIM, IDIM);
    k_ln_router<<<dim3(T_TOK), dim3(256), 0, stream>>>(x, rlw, rlb, rw, rb, xhat, counts, ltok, lwt);
    k_offs<<<dim3(1), dim3(64), 0, stream>>>(counts, offs);
    k_ag_build<<<dim3(32, 4, NEXP), dim3(256), 0, stream>>>(xhat, elw, elb, counts, offs, ltok, ag);
    k_gemm1<<<dim3(32, 32, NEXP), dim3(256), 0, stream>>>(ag, wbf, b1, counts, offs, hbuf);
    // w2 [E][I][H] -> wbf [E][H][I] bf16 (reuses buffer; Ag region becomes eo)
    k_cvt_t<<<dim3(HDIM / 64, IDIM / 64, NEXP), dim3(256), 0, stream>>>(w2, wbf, IDIM, HDIM);
    k_gemm2<<<dim3(32, 8, NEXP), dim3(256), 0, stream>>>(hbuf, wbf, b2, counts, offs, ltok, lwt, eo);
    k_final<<<dim3(T_TOK), dim3(256), 0, stream>>>(eo, ow, ob, out);
}

// Round 4
// 727.919 us; speedup vs baseline: 3.8776x; 1.7597x over previous
//
#include <hip/hip_runtime.h>
#include <hip/hip_bf16.h>

#define T_TOK 4096
#define HDIM 1024
#define IDIM 4096
#define NEXP 8

typedef __bf16 bf16x8 __attribute__((ext_vector_type(8)));
typedef float f32x4 __attribute__((ext_vector_type(4)));
typedef unsigned short us8 __attribute__((ext_vector_type(8)));

__device__ __forceinline__ unsigned short f2bf(float f) {
    union { float f; unsigned int u; } v; v.f = f;
    unsigned int u = v.u;
    unsigned int r = u + 0x7fffu + ((u >> 16) & 1u);
    return (unsigned short)(r >> 16);
}
__device__ __forceinline__ float bf2f(unsigned short b) {
    union { unsigned int u; float f; } v; v.u = ((unsigned int)b) << 16;
    return v.f;
}

// async 16B/lane global->LDS: wave-uniform lds base, lane l lands at base + l*16
__device__ __forceinline__ void gll16(const unsigned short* g, unsigned short* lds) {
    __builtin_amdgcn_global_load_lds(
        (const __attribute__((address_space(1))) unsigned int*)g,
        (__attribute__((address_space(3))) unsigned int*)lds, 16, 0, 0);
}

// Abramowitz-Stegun 7.1.26 erf (|err| <= 1.5e-7), exact-erf GELU
__device__ __forceinline__ float gelu_f(float v) {
    float x = v * 0.70710678118654752f;
    float ax = fabsf(x);
    float t = __builtin_amdgcn_rcpf(1.0f + 0.3275911f * ax);
    float p = t * (0.254829592f + t * (-0.284496736f + t * (1.421413741f
              + t * (-1.453152027f + t * 1.061405429f))));
    float ex = __expf(-x * x);
    float er = 1.0f - p * ex;
    er = copysignf(er, x);
    return 0.5f * v * (1.0f + er);
}

// ---------------- transpose+convert: src [E][R][C] f32 -> dst [E][C][R] bf16 ----------------
__global__ __launch_bounds__(256) void k_cvt_t(const float* __restrict__ src,
                                               unsigned short* __restrict__ dst,
                                               int R, int C) {
    __shared__ unsigned short tl[64][72];
    const int e = blockIdx.z;
    const int c0 = blockIdx.x * 64, r0 = blockIdx.y * 64;
    const int tid = threadIdx.x;
    #pragma unroll
    for (int it = 0; it < 4; it++) {
        int idx = it * 256 + tid;
        int rl = idx >> 4, cl = (idx & 15) * 4;
        float4 v = *(const float4*)(src + ((size_t)e * R + r0 + rl) * C + c0 + cl);
        tl[cl + 0][rl] = f2bf(v.x);
        tl[cl + 1][rl] = f2bf(v.y);
        tl[cl + 2][rl] = f2bf(v.z);
        tl[cl + 3][rl] = f2bf(v.w);
    }
    __syncthreads();
    #pragma unroll
    for (int it = 0; it < 2; it++) {
        int idx = it * 256 + tid;
        int cl = idx >> 3, ch = idx & 7;
        us8 v;
        __builtin_memcpy(&v, &tl[cl][ch * 8], 16);
        *(us8*)(dst + ((size_t)e * C + c0 + cl) * R + r0 + ch * 8) = v;
    }
}

// ---------------- LN stats + router top-2 + routing lists ----------------
__global__ __launch_bounds__(256) void k_ln_router(
    const float* __restrict__ x, const float* __restrict__ rlw, const float* __restrict__ rlb,
    const float* __restrict__ rw, const float* __restrict__ rb,
    unsigned short* __restrict__ xhat, int* __restrict__ counts,
    int* __restrict__ ltok, float* __restrict__ lwt)
{
    const int t = blockIdx.x, tid = threadIdx.x;
    const float4 v = *(const float4*)(x + (size_t)t * HDIM + tid * 4);
    float s  = v.x + v.y + v.z + v.w;
    float sq = v.x*v.x + v.y*v.y + v.z*v.z + v.w*v.w;
    for (int o = 32; o > 0; o >>= 1) { s += __shfl_xor(s, o); sq += __shfl_xor(sq, o); }
    __shared__ float red[8];
    __shared__ float stats[2];
    const int wid = tid >> 6, lane = tid & 63;
    if (lane == 0) { red[wid] = s; red[4 + wid] = sq; }
    __syncthreads();
    if (tid == 0) {
        float S = red[0] + red[1] + red[2] + red[3];
        float Q = red[4] + red[5] + red[6] + red[7];
        float mu = S / (float)HDIM;
        float var = Q / (float)HDIM - mu * mu;
        stats[0] = mu; stats[1] = rsqrtf(var + 1e-5f);
    }
    __syncthreads();
    const float mu = stats[0], rstd = stats[1];
    float xh[4];
    xh[0] = (v.x - mu) * rstd; xh[1] = (v.y - mu) * rstd;
    xh[2] = (v.z - mu) * rstd; xh[3] = (v.w - mu) * rstd;
    ushort4 o4;
    o4.x = f2bf(xh[0]); o4.y = f2bf(xh[1]); o4.z = f2bf(xh[2]); o4.w = f2bf(xh[3]);
    *(ushort4*)(xhat + (size_t)t * HDIM + tid * 4) = o4;

    float p[8];
    #pragma unroll
    for (int e = 0; e < 8; e++) p[e] = 0.f;
    const float4 w4 = *(const float4*)(rlw + tid * 4);
    const float4 b4 = *(const float4*)(rlb + tid * 4);
    const float wl[4] = { w4.x, w4.y, w4.z, w4.w };
    const float bl[4] = { b4.x, b4.y, b4.z, b4.w };
    #pragma unroll
    for (int j = 0; j < 4; j++) {
        float rl = xh[j] * wl[j] + bl[j];
        const float* wr = rw + (size_t)(tid * 4 + j) * 8;
        float4 wa = *(const float4*)(wr);
        float4 wb = *(const float4*)(wr + 4);
        p[0] += rl * wa.x; p[1] += rl * wa.y; p[2] += rl * wa.z; p[3] += rl * wa.w;
        p[4] += rl * wb.x; p[5] += rl * wb.y; p[6] += rl * wb.z; p[7] += rl * wb.w;
    }
    #pragma unroll
    for (int e = 0; e < 8; e++)
        for (int o = 32; o > 0; o >>= 1) p[e] += __shfl_xor(p[e], o);
    __shared__ float pw[4][8];
    if (lane == 0) {
        #pragma unroll
        for (int e = 0; e < 8; e++) pw[wid][e] = p[e];
    }
    __syncthreads();
    if (tid == 0) {
        float lg[8];
        #pragma unroll
        for (int e = 0; e < 8; e++)
            lg[e] = pw[0][e] + pw[1][e] + pw[2][e] + pw[3][e] + rb[e];
        int i0 = 0;
        #pragma unroll
        for (int e = 1; e < 8; e++) if (lg[e] > lg[i0]) i0 = e;
        int i1 = (i0 == 0) ? 1 : 0;
        #pragma unroll
        for (int e = 0; e < 8; e++) if (e != i0 && lg[e] > lg[i1]) i1 = e;
        float e1 = expf(lg[i1] - lg[i0]);
        float w0 = 1.f / (1.f + e1);
        float w1 = 1.f - w0;
        int p0 = atomicAdd(&counts[i0], 1);
        ltok[i0 * T_TOK + p0] = t * 2 + 0; lwt[i0 * T_TOK + p0] = w0;
        int p1 = atomicAdd(&counts[i1], 1);
        ltok[i1 * T_TOK + p1] = t * 2 + 1; lwt[i1 * T_TOK + p1] = w1;
    }
}

// ---------------- tiny prefix sum ----------------
__global__ void k_offs(const int* __restrict__ counts, int* __restrict__ offs) {
    if (threadIdx.x == 0 && blockIdx.x == 0) {
        int a = 0;
        for (int e = 0; e < NEXP; e++) { offs[e] = a; a += counts[e]; }
        offs[NEXP] = a;
    }
}

// ---------------- build packed, expert-LN-affined A (bf16) ----------------
__global__ __launch_bounds__(256) void k_ag_build(
    const unsigned short* __restrict__ xhat, const float* __restrict__ elw, const float* __restrict__ elb,
    const int* __restrict__ counts, const int* __restrict__ offs, const int* __restrict__ ltok,
    unsigned short* __restrict__ ag)
{
    const int e = blockIdx.z, rt = blockIdx.x, cc = blockIdx.y;
    const int ne = counts[e];
    if (rt * 128 >= ne) return;
    const int off = offs[e];
    const int tid = threadIdx.x;
    const int row = rt * 128 + (tid >> 1);
    if (row >= ne) return;
    const int tok = ltok[e * T_TOK + row] >> 1;
    const int cb = cc * 256 + (tid & 1) * 128;
    const unsigned short* src = xhat + (size_t)tok * HDIM + cb;
    unsigned short* dst = ag + (size_t)(off + row) * HDIM + cb;
    const float* wv = elw + (size_t)e * HDIM + cb;
    const float* bv = elb + (size_t)e * HDIM + cb;
    #pragma unroll
    for (int j = 0; j < 128; j += 8) {
        us8 xv = *(const us8*)(src + j);
        us8 o;
        #pragma unroll
        for (int q = 0; q < 8; q++)
            o[q] = f2bf(bf2f(xv[q]) * wv[j + q] + bv[j + q]);
        *(us8*)(dst + j) = o;
    }
}

// ======================= pipelined grouped GEMMs =======================
// blockIdx.x = ct (fastest -> XCD id%8 keeps a fixed set of B stripes in its L2)
// LDS: double-buffered 128x64 bf16 tiles for A and B (64 KB), staged via
// global_load_lds w=16 with XOR(k-chunk, row&7) swizzle for conflict-free reads.
// K-loop: stage(k+1) -> s_waitcnt vmcnt(8) (own prev-tile only) -> s_barrier ->
// MFMA on tile k -> s_barrier.  No vmcnt(0) drain inside the loop.

#define GEMM_STAGE(gA, gB, ldst, ko, KSTRIDE)                                   \
    {                                                                           \
        _Pragma("unroll")                                                       \
        for (int i_ = 0; i_ < 4; i_++) {                                        \
            gll16(gA + (size_t)(8 * i_) * KSTRIDE + (ko), ldst##A + i_ * 512);  \
            gll16(gB + (size_t)(8 * i_) * KSTRIDE + (ko), ldst##B + i_ * 512);  \
        }                                                                       \
    }

#define GEMM_COMPUTE(ASb, BSb)                                                  \
    {                                                                           \
        _Pragma("unroll")                                                       \
        for (int ks_ = 0; ks_ < 64; ks_ += 32) {                                \
            const int ch_ = ks_ >> 3;                                           \
            bf16x8 af[4], bfr[4];                                               \
            _Pragma("unroll")                                                   \
            for (int i_ = 0; i_ < 4; i_++)                                      \
                __builtin_memcpy(&af[i_],                                       \
                    (ASb) + (wm + i_ * 16 + fr) * 64                            \
                          + (((quad + ch_) ^ (fr & 7)) * 8), 16);               \
            _Pragma("unroll")                                                   \
            for (int j_ = 0; j_ < 4; j_++)                                      \
                __builtin_memcpy(&bfr[j_],                                      \
                    (BSb) + (wn + j_ * 16 + fr) * 64                            \
                          + (((quad + ch_) ^ (fr & 7)) * 8), 16);               \
            _Pragma("unroll")                                                   \
            for (int i_ = 0; i_ < 4; i_++)                                      \
                _Pragma("unroll")                                               \
                for (int j_ = 0; j_ < 4; j_++)                                  \
                    acc[i_][j_] = __builtin_amdgcn_mfma_f32_16x16x32_bf16(      \
                        af[i_], bfr[j_], acc[i_][j_], 0, 0, 0);                 \
        }                                                                       \
    }

// ---------------- GEMM1: Ag @ w1bf^T -> +b1 -> gelu -> hbuf (bf16) ----------------
__global__ __launch_bounds__(256) void k_gemm1(
    const unsigned short* __restrict__ ag, const unsigned short* __restrict__ wbf,
    const float* __restrict__ b1,
    const int* __restrict__ counts, const int* __restrict__ offs,
    unsigned short* __restrict__ hbuf)
{
    const int ct = blockIdx.x, rt = blockIdx.y, e = blockIdx.z;
    const int ne = counts[e];
    if (rt * 128 >= ne) return;
    const int off = offs[e];
    __shared__ unsigned short As[2][128 * 64];
    __shared__ unsigned short Bs[2][128 * 64];
    const int tid = threadIdx.x, wid = tid >> 6, lane = tid & 63;
    const int lrow = lane >> 3, lchunk = (lane ^ lrow) & 7;

    const unsigned short* gA = ag + (size_t)(off + rt * 128 + 32 * wid + lrow) * HDIM + lchunk * 8;
    const unsigned short* gB = wbf + (size_t)e * IDIM * HDIM
                             + (size_t)(ct * 128 + 32 * wid + lrow) * HDIM + lchunk * 8;

    f32x4 acc[4][4];
    #pragma unroll
    for (int i = 0; i < 4; i++)
        #pragma unroll
        for (int j = 0; j < 4; j++) acc[i][j] = (f32x4){0.f, 0.f, 0.f, 0.f};

    const int wm = (wid & 1) * 64, wn = (wid >> 1) * 64;
    const int fr = lane & 15, quad = lane >> 4;

    unsigned short* l0A = &As[0][wid * 2048];
    unsigned short* l0B = &Bs[0][wid * 2048];
    unsigned short* l1A = &As[1][wid * 2048];
    unsigned short* l1B = &Bs[1][wid * 2048];

    const int NK = HDIM / 64;  // 16
    GEMM_STAGE(gA, gB, l0, 0, HDIM);
    #pragma unroll 1
    for (int kt = 0; kt < NK - 1; ++kt) {
        const int b = kt & 1;
        if (b == 0) { GEMM_STAGE(gA, gB, l1, (kt + 1) * 64, HDIM); }
        else        { GEMM_STAGE(gA, gB, l0, (kt + 1) * 64, HDIM); }
        asm volatile("s_waitcnt vmcnt(8)" ::: "memory");
        asm volatile("s_barrier" ::: "memory");
        GEMM_COMPUTE(&As[b][0], &Bs[b][0]);
        asm volatile("s_barrier" ::: "memory");
    }
    asm volatile("s_waitcnt vmcnt(0)" ::: "memory");
    asm volatile("s_barrier" ::: "memory");
    GEMM_COMPUTE(&As[(NK - 1) & 1][0], &Bs[(NK - 1) & 1][0]);

    // epilogue: + b1, gelu(erf), -> bf16 h
    float bias[4];
    #pragma unroll
    for (int j = 0; j < 4; j++) bias[j] = b1[e * IDIM + ct * 128 + wn + j * 16 + fr];
    #pragma unroll
    for (int i = 0; i < 4; i++) {
        #pragma unroll
        for (int rg = 0; rg < 4; rg++) {
            const int r = rt * 128 + wm + i * 16 + quad * 4 + rg;
            if (r < ne) {
                unsigned short* hrow = hbuf + (size_t)(off + r) * IDIM + ct * 128 + wn + fr;
                #pragma unroll
                for (int j = 0; j < 4; j++)
                    hrow[j * 16] = f2bf(gelu_f(acc[i][j][rg] + bias[j]));
            }
        }
    }
}

// ---------------- GEMM2: hbuf @ w2bf -> +b2 -> *wt -> eo[t,slot,:] ----------------
__global__ __launch_bounds__(256) void k_gemm2(
    const unsigned short* __restrict__ hbuf, const unsigned short* __restrict__ wbf,
    const float* __restrict__ b2,
    const int* __restrict__ counts, const int* __restrict__ offs,
    const int* __restrict__ ltok, const float* __restrict__ lwt,
    float* __restrict__ eo)
{
    const int ct = blockIdx.x, rt = blockIdx.y, e = blockIdx.z;
    const int ne = counts[e];
    if (rt * 128 >= ne) return;
    const int off = offs[e];
    __shared__ unsigned short As[2][128 * 64];
    __shared__ unsigned short Bs[2][128 * 64];
    const int tid = threadIdx.x, wid = tid >> 6, lane = tid & 63;
    const int lrow = lane >> 3, lchunk = (lane ^ lrow) & 7;

    const unsigned short* gA = hbuf + (size_t)(off + rt * 128 + 32 * wid + lrow) * IDIM + lchunk * 8;
    const unsigned short* gB = wbf + (size_t)e * HDIM * IDIM
                             + (size_t)(ct * 128 + 32 * wid + lrow) * IDIM + lchunk * 8;

    f32x4 acc[4][4];
    #pragma unroll
    for (int i = 0; i < 4; i++)
        #pragma unroll
        for (int j = 0; j < 4; j++) acc[i][j] = (f32x4){0.f, 0.f, 0.f, 0.f};

    const int wm = (wid & 1) * 64, wn = (wid >> 1) * 64;
    const int fr = lane & 15, quad = lane >> 4;

    unsigned short* l0A = &As[0][wid * 2048];
    unsigned short* l0B = &Bs[0][wid * 2048];
    unsigned short* l1A = &As[1][wid * 2048];
    unsigned short* l1B = &Bs[1][wid * 2048];

    const int NK = IDIM / 64;  // 64
    GEMM_STAGE(gA, gB, l0, 0, IDIM);
    #pragma unroll 1
    for (int kt = 0; kt < NK - 1; ++kt) {
        const int b = kt & 1;
        if (b == 0) { GEMM_STAGE(gA, gB, l1, (kt + 1) * 64, IDIM); }
        else        { GEMM_STAGE(gA, gB, l0, (kt + 1) * 64, IDIM); }
        asm volatile("s_waitcnt vmcnt(8)" ::: "memory");
        asm volatile("s_barrier" ::: "memory");
        GEMM_COMPUTE(&As[b][0], &Bs[b][0]);
        asm volatile("s_barrier" ::: "memory");
    }
    asm volatile("s_waitcnt vmcnt(0)" ::: "memory");
    asm volatile("s_barrier" ::: "memory");
    GEMM_COMPUTE(&As[(NK - 1) & 1][0], &Bs[(NK - 1) & 1][0]);

    // epilogue: + b2, * routing weight, scatter fp32 to eo[token*2+slot]
    float bias[4];
    #pragma unroll
    for (int j = 0; j < 4; j++) bias[j] = b2[e * HDIM + ct * 128 + wn + j * 16 + fr];
    #pragma unroll
    for (int i = 0; i < 4; i++) {
        #pragma unroll
        for (int rg = 0; rg < 4; rg++) {
            const int r = rt * 128 + wm + i * 16 + quad * 4 + rg;
            if (r < ne) {
                const int d = ltok[e * T_TOK + r];
                const float w = lwt[e * T_TOK + r];
                float* erow = eo + (size_t)d * HDIM + ct * 128 + wn + fr;
                #pragma unroll
                for (int j = 0; j < 4; j++)
                    erow[j * 16] = (acc[i][j][rg] + bias[j]) * w;
            }
        }
    }
}

// ---------------- combine + final LN ----------------
__global__ __launch_bounds__(256) void k_final(
    const float* __restrict__ eo, const float* __restrict__ ow, const float* __restrict__ ob,
    float* __restrict__ out)
{
    const int t = blockIdx.x, tid = threadIdx.x;
    const float4 a = *(const float4*)(eo + (size_t)(t * 2 + 0) * HDIM + tid * 4);
    const float4 b = *(const float4*)(eo + (size_t)(t * 2 + 1) * HDIM + tid * 4);
    float c0 = a.x + b.x, c1 = a.y + b.y, c2 = a.z + b.z, c3 = a.w + b.w;
    float s = c0 + c1 + c2 + c3;
    float sq = c0*c0 + c1*c1 + c2*c2 + c3*c3;
    for (int o = 32; o > 0; o >>= 1) { s += __shfl_xor(s, o); sq += __shfl_xor(sq, o); }
    __shared__ float red[8];
    __shared__ float stats[2];
    const int wid = tid >> 6, lane = tid & 63;
    if (lane == 0) { red[wid] = s; red[4 + wid] = sq; }
    __syncthreads();
    if (tid == 0) {
        float S = red[0] + red[1] + red[2] + red[3];
        float Q = red[4] + red[5] + red[6] + red[7];
        float mu = S / (float)HDIM;
        float var = Q / (float)HDIM - mu * mu;
        stats[0] = mu; stats[1] = rsqrtf(var + 1e-5f);
    }
    __syncthreads();
    const float mu = stats[0], rstd = stats[1];
    const float4 w4 = *(const float4*)(ow + tid * 4);
    const float4 b4 = *(const float4*)(ob + tid * 4);
    float4 o;
    o.x = (c0 - mu) * rstd * w4.x + b4.x;
    o.y = (c1 - mu) * rstd * w4.y + b4.y;
    o.z = (c2 - mu) * rstd * w4.z + b4.z;
    o.w = (c3 - mu) * rstd * w4.w + b4.w;
    *(float4*)(out + (size_t)t * HDIM + tid * 4) = o;
}

extern "C" void kernel_launch(void* const* d_in, const int* in_sizes, int n_in,
                              void* d_out, int out_size, void* d_ws, size_t ws_size,
                              hipStream_t stream) {
    const float* x   = (const float*)d_in[0];
    const float* rlw = (const float*)d_in[1];
    const float* rlb = (const float*)d_in[2];
    const float* rw  = (const float*)d_in[3];
    const float* rb  = (const float*)d_in[4];
    const float* elw = (const float*)d_in[5];
    const float* elb = (const float*)d_in[6];
    const float* w1  = (const float*)d_in[7];
    const float* b1  = (const float*)d_in[8];
    const float* w2  = (const float*)d_in[9];
    const float* b2  = (const float*)d_in[10];
    const float* ow  = (const float*)d_in[11];
    const float* ob  = (const float*)d_in[12];
    float* out = (float*)d_out;

    char* ws = (char*)d_ws;
    // layout (~160.3 MB):
    //   [0, 64MB):    wbf  — w1 bf16 [E][I][H] for GEMM1, then w2 bf16 [E][H][I] for GEMM2
    //   [64, 128MB):  hbuf bf16 [8192][IDIM]; xhat bf16 [T][H] (8MB) lives at its base until GEMM1
    //   [128MB, +32MB): Ag bf16 (17MB, dead after GEMM1) overlapped by eo fp32 [T][2][H] (32MB)
    //   then: ltok[8][T], lwt[8][T], counts[8], offs[9]
    const size_t MB = 1024 * 1024;
    unsigned short* wbf  = (unsigned short*)(ws);
    unsigned short* hbuf = (unsigned short*)(ws + 64 * MB);
    unsigned short* xhat = (unsigned short*)(ws + 64 * MB);
    unsigned short* ag   = (unsigned short*)(ws + 128 * MB);
    float* eo            = (float*)(ws + 128 * MB);
    char* tail           = ws + 160 * MB;
    int* ltok            = (int*)(tail);
    float* lwt           = (float*)(tail + 131072);
    int* counts          = (int*)(tail + 262144);
    int* offs            = (int*)(tail + 262144 + 64);

    hipMemsetAsync(counts, 0, 8 * sizeof(int), stream);
    // w1 [E][H][I] -> wbf [E][I][H] bf16
    k_cvt_t<<<dim3(IDIM / 64, HDIM / 64, NEXP), dim3(256), 0, stream>>>(w1, wbf, HDIM, IDIM);
    k_ln_router<<<dim3(T_TOK), dim3(256), 0, stream>>>(x, rlw, rlb, rw, rb, xhat, counts, ltok, lwt);
    k_offs<<<dim3(1), dim3(64), 0, stream>>>(counts, offs);
    k_ag_build<<<dim3(32, 4, NEXP), dim3(256), 0, stream>>>(xhat, elw, elb, counts, offs, ltok, ag);
    // grid: x=ct (XCD-affine B stripes), y=rt, z=expert
    k_gemm1<<<dim3(32, 32, NEXP), dim3(256), 0, stream>>>(ag, wbf, b1, counts, offs, hbuf);
    // w2 [E][I][H] -> wbf [E][H][I] bf16 (reuses buffer; Ag region becomes eo)
    k_cvt_t<<<dim3(HDIM / 64, IDIM / 64, NEXP), dim3(256), 0, stream>>>(w2, wbf, IDIM, HDIM);
    k_gemm2<<<dim3(8, 32, NEXP), dim3(256), 0, stream>>>(hbuf, wbf, b2, counts, offs, ltok, lwt, eo);
    k_final<<<dim3(T_TOK), dim3(256), 0, stream>>>(eo, ow, ob, out);
}

// Round 5
// 715.017 us; speedup vs baseline: 3.9475x; 1.0180x over previous
//
#include <hip/hip_runtime.h>
#include <hip/hip_bf16.h>

#define T_TOK 4096
#define HDIM 1024
#define IDIM 4096
#define NEXP 8
#define MAXRB 72

typedef __bf16 bf16x8 __attribute__((ext_vector_type(8)));
typedef float f32x4 __attribute__((ext_vector_type(4)));
typedef unsigned short us8 __attribute__((ext_vector_type(8)));

__device__ __forceinline__ unsigned short f2bf(float f) {
    union { float f; unsigned int u; } v; v.f = f;
    unsigned int u = v.u;
    unsigned int r = u + 0x7fffu + ((u >> 16) & 1u);
    return (unsigned short)(r >> 16);
}
__device__ __forceinline__ float bf2f(unsigned short b) {
    union { unsigned int u; float f; } v; v.u = ((unsigned int)b) << 16;
    return v.f;
}

// async 16B/lane global->LDS: wave-uniform lds base, lane l lands at base + l*16
__device__ __forceinline__ void gll16(const unsigned short* g, unsigned short* lds) {
    __builtin_amdgcn_global_load_lds(
        (const __attribute__((address_space(1))) unsigned int*)g,
        (__attribute__((address_space(3))) unsigned int*)lds, 16, 0, 0);
}

// Abramowitz-Stegun 7.1.26 erf (|err| <= 1.5e-7), exact-erf GELU
__device__ __forceinline__ float gelu_f(float v) {
    float x = v * 0.70710678118654752f;
    float ax = fabsf(x);
    float t = __builtin_amdgcn_rcpf(1.0f + 0.3275911f * ax);
    float p = t * (0.254829592f + t * (-0.284496736f + t * (1.421413741f
              + t * (-1.453152027f + t * 1.061405429f))));
    float ex = __expf(-x * x);
    float er = 1.0f - p * ex;
    er = copysignf(er, x);
    return 0.5f * v * (1.0f + er);
}

// ---------------- transpose+convert: src [E][R][C] f32 -> dst [E][C][R] bf16 ----------------
__global__ __launch_bounds__(256) void k_cvt_t(const float* __restrict__ src,
                                               unsigned short* __restrict__ dst,
                                               int R, int C) {
    __shared__ unsigned short tl[64][72];
    const int e = blockIdx.z;
    const int c0 = blockIdx.x * 64, r0 = blockIdx.y * 64;
    const int tid = threadIdx.x;
    #pragma unroll
    for (int it = 0; it < 4; it++) {
        int idx = it * 256 + tid;
        int rl = idx >> 4, cl = (idx & 15) * 4;
        float4 v = *(const float4*)(src + ((size_t)e * R + r0 + rl) * C + c0 + cl);
        tl[cl + 0][rl] = f2bf(v.x);
        tl[cl + 1][rl] = f2bf(v.y);
        tl[cl + 2][rl] = f2bf(v.z);
        tl[cl + 3][rl] = f2bf(v.w);
    }
    __syncthreads();
    #pragma unroll
    for (int it = 0; it < 2; it++) {
        int idx = it * 256 + tid;
        int cl = idx >> 3, ch = idx & 7;
        us8 v;
        __builtin_memcpy(&v, &tl[cl][ch * 8], 16);
        *(us8*)(dst + ((size_t)e * C + c0 + cl) * R + r0 + ch * 8) = v;
    }
}

// ---------------- LN stats + router top-2 + routing lists ----------------
__global__ __launch_bounds__(256) void k_ln_router(
    const float* __restrict__ x, const float* __restrict__ rlw, const float* __restrict__ rlb,
    const float* __restrict__ rw, const float* __restrict__ rb,
    unsigned short* __restrict__ xhat, int* __restrict__ counts,
    int* __restrict__ ltok, float* __restrict__ lwt)
{
    const int t = blockIdx.x, tid = threadIdx.x;
    const float4 v = *(const float4*)(x + (size_t)t * HDIM + tid * 4);
    float s  = v.x + v.y + v.z + v.w;
    float sq = v.x*v.x + v.y*v.y + v.z*v.z + v.w*v.w;
    for (int o = 32; o > 0; o >>= 1) { s += __shfl_xor(s, o); sq += __shfl_xor(sq, o); }
    __shared__ float red[8];
    __shared__ float stats[2];
    const int wid = tid >> 6, lane = tid & 63;
    if (lane == 0) { red[wid] = s; red[4 + wid] = sq; }
    __syncthreads();
    if (tid == 0) {
        float S = red[0] + red[1] + red[2] + red[3];
        float Q = red[4] + red[5] + red[6] + red[7];
        float mu = S / (float)HDIM;
        float var = Q / (float)HDIM - mu * mu;
        stats[0] = mu; stats[1] = rsqrtf(var + 1e-5f);
    }
    __syncthreads();
    const float mu = stats[0], rstd = stats[1];
    float xh[4];
    xh[0] = (v.x - mu) * rstd; xh[1] = (v.y - mu) * rstd;
    xh[2] = (v.z - mu) * rstd; xh[3] = (v.w - mu) * rstd;
    ushort4 o4;
    o4.x = f2bf(xh[0]); o4.y = f2bf(xh[1]); o4.z = f2bf(xh[2]); o4.w = f2bf(xh[3]);
    *(ushort4*)(xhat + (size_t)t * HDIM + tid * 4) = o4;

    float p[8];
    #pragma unroll
    for (int e = 0; e < 8; e++) p[e] = 0.f;
    const float4 w4 = *(const float4*)(rlw + tid * 4);
    const float4 b4 = *(const float4*)(rlb + tid * 4);
    const float wl[4] = { w4.x, w4.y, w4.z, w4.w };
    const float bl[4] = { b4.x, b4.y, b4.z, b4.w };
    #pragma unroll
    for (int j = 0; j < 4; j++) {
        float rl = xh[j] * wl[j] + bl[j];
        const float* wr = rw + (size_t)(tid * 4 + j) * 8;
        float4 wa = *(const float4*)(wr);
        float4 wb = *(const float4*)(wr + 4);
        p[0] += rl * wa.x; p[1] += rl * wa.y; p[2] += rl * wa.z; p[3] += rl * wa.w;
        p[4] += rl * wb.x; p[5] += rl * wb.y; p[6] += rl * wb.z; p[7] += rl * wb.w;
    }
    #pragma unroll
    for (int e = 0; e < 8; e++)
        for (int o = 32; o > 0; o >>= 1) p[e] += __shfl_xor(p[e], o);
    __shared__ float pw[4][8];
    if (lane == 0) {
        #pragma unroll
        for (int e = 0; e < 8; e++) pw[wid][e] = p[e];
    }
    __syncthreads();
    if (tid == 0) {
        float lg[8];
        #pragma unroll
        for (int e = 0; e < 8; e++)
            lg[e] = pw[0][e] + pw[1][e] + pw[2][e] + pw[3][e] + rb[e];
        int i0 = 0;
        #pragma unroll
        for (int e = 1; e < 8; e++) if (lg[e] > lg[i0]) i0 = e;
        int i1 = (i0 == 0) ? 1 : 0;
        #pragma unroll
        for (int e = 0; e < 8; e++) if (e != i0 && lg[e] > lg[i1]) i1 = e;
        float e1 = expf(lg[i1] - lg[i0]);
        float w0 = 1.f / (1.f + e1);
        float w1 = 1.f - w0;
        int p0 = atomicAdd(&counts[i0], 1);
        ltok[i0 * T_TOK + p0] = t * 2 + 0; lwt[i0 * T_TOK + p0] = w0;
        int p1 = atomicAdd(&counts[i1], 1);
        ltok[i1 * T_TOK + p1] = t * 2 + 1; lwt[i1 * T_TOK + p1] = w1;
    }
}

// ---------------- prefix sum + row-block schedule table ----------------
__global__ void k_sched(const int* __restrict__ counts, int* __restrict__ offs,
                        int* __restrict__ rb_e, int* __restrict__ rb_rt) {
    if (threadIdx.x == 0 && blockIdx.x == 0) {
        int a = 0;
        for (int e = 0; e < NEXP; e++) { offs[e] = a; a += counts[e]; }
        offs[NEXP] = a;
        int i = 0;
        for (int e = 0; e < NEXP; e++) {
            int nrb = (counts[e] + 127) >> 7;
            for (int rt = 0; rt < nrb; rt++) { rb_e[i] = e; rb_rt[i] = rt; i++; }
        }
        for (; i < MAXRB; i++) { rb_e[i] = -1; rb_rt[i] = 0; }
    }
}

// ---------------- build packed, expert-LN-affined A (bf16) ----------------
__global__ __launch_bounds__(256) void k_ag_build(
    const unsigned short* __restrict__ xhat, const float* __restrict__ elw, const float* __restrict__ elb,
    const int* __restrict__ counts, const int* __restrict__ offs, const int* __restrict__ ltok,
    unsigned short* __restrict__ ag)
{
    const int e = blockIdx.z, rt = blockIdx.x, cc = blockIdx.y;
    const int ne = counts[e];
    if (rt * 128 >= ne) return;
    const int off = offs[e];
    const int tid = threadIdx.x;
    const int row = rt * 128 + (tid >> 1);
    if (row >= ne) return;
    const int tok = ltok[e * T_TOK + row] >> 1;
    const int cb = cc * 256 + (tid & 1) * 128;
    const unsigned short* src = xhat + (size_t)tok * HDIM + cb;
    unsigned short* dst = ag + (size_t)(off + row) * HDIM + cb;
    const float* wv = elw + (size_t)e * HDIM + cb;
    const float* bv = elb + (size_t)e * HDIM + cb;
    #pragma unroll
    for (int j = 0; j < 128; j += 8) {
        us8 xv = *(const us8*)(src + j);
        us8 o;
        #pragma unroll
        for (int q = 0; q < 8; q++)
            o[q] = f2bf(bf2f(xv[q]) * wv[j + q] + bv[j + q]);
        *(us8*)(dst + j) = o;
    }
}

// ======================= pipelined grouped GEMMs (BK=32, 32 KB LDS dbuf) ===============
// blockIdx.x = ct (fastest -> XCD id%8 locks B stripes per XCD L2)
// blockIdx.y = row-block schedule index (device-built table, no early-exit flood)
// LDS tile 128x32 bf16, row = 64 B. Swizzle: stored_chunk = global_chunk ^ ((row>>1)&3)
//   -> both DMA writes and ds_read_b128 are conflict-free per 8-lane phase.
// K-loop: stage(k+1 -> other buf, 4 DMA/wave) -> s_waitcnt vmcnt(4) -> barrier ->
//         16 MFMA on buf k -> barrier. Never vmcnt(0) inside the loop.

#define GEMM_COMPUTE32(ASb, BSb)                                                \
    {                                                                           \
        bf16x8 af[4], bfr[4];                                                   \
        const int sw_ = (quad ^ ((fr >> 1) & 3)) * 8;                           \
        _Pragma("unroll")                                                       \
        for (int i_ = 0; i_ < 4; i_++)                                          \
            __builtin_memcpy(&af[i_], (ASb) + (wm + i_ * 16 + fr) * 32 + sw_, 16);\
        _Pragma("unroll")                                                       \
        for (int j_ = 0; j_ < 4; j_++)                                          \
            __builtin_memcpy(&bfr[j_], (BSb) + (wn + j_ * 16 + fr) * 32 + sw_, 16);\
        _Pragma("unroll")                                                       \
        for (int i_ = 0; i_ < 4; i_++)                                          \
            _Pragma("unroll")                                                   \
            for (int j_ = 0; j_ < 4; j_++)                                      \
                acc[i_][j_] = __builtin_amdgcn_mfma_f32_16x16x32_bf16(          \
                    af[i_], bfr[j_], acc[i_][j_], 0, 0, 0);                     \
    }

// ---------------- GEMM1: Ag @ w1bf^T -> +b1 -> gelu -> hbuf (bf16) ----------------
__global__ __launch_bounds__(256, 5) void k_gemm1(
    const unsigned short* __restrict__ ag, const unsigned short* __restrict__ wbf,
    const float* __restrict__ b1,
    const int* __restrict__ counts, const int* __restrict__ offs,
    const int* __restrict__ rb_e, const int* __restrict__ rb_rt,
    unsigned short* __restrict__ hbuf)
{
    const int e = rb_e[blockIdx.y];
    if (e < 0) return;
    const int rt = rb_rt[blockIdx.y], ct = blockIdx.x;
    const int ne = counts[e], off = offs[e];
    __shared__ unsigned short As[2 * 128 * 32];
    __shared__ unsigned short Bs[2 * 128 * 32];
    const int tid = threadIdx.x, wid = tid >> 6, lane = tid & 63;
    // staging lane map: row = 32*wid + 16*i_ + (lane>>2); fetch k-chunk = (lane&3)^((lane>>3)&3)
    const int srow = 32 * wid + (lane >> 2);
    const int kswz = ((lane & 3) ^ ((lane >> 3) & 3)) * 8;
    const unsigned short* gA = ag + (size_t)(off + rt * 128 + srow) * HDIM + kswz;
    const unsigned short* gB = wbf + (size_t)e * IDIM * HDIM
                             + (size_t)(ct * 128 + srow) * HDIM + kswz;
    const int wso = wid * 1024;

    f32x4 acc[4][4];
    #pragma unroll
    for (int i = 0; i < 4; i++)
        #pragma unroll
        for (int j = 0; j < 4; j++) acc[i][j] = (f32x4){0.f, 0.f, 0.f, 0.f};

    const int wm = (wid & 1) * 64, wn = (wid >> 1) * 64;
    const int fr = lane & 15, quad = lane >> 4;

    const int NK = HDIM / 32;  // 32
    {   // prologue -> buf 0
        unsigned short* dA = As + wso;
        unsigned short* dB = Bs + wso;
        gll16(gA, dA); gll16(gA + (size_t)16 * HDIM, dA + 512);
        gll16(gB, dB); gll16(gB + (size_t)16 * HDIM, dB + 512);
    }
    #pragma unroll 1
    for (int kt = 0; kt < NK - 1; ++kt) {
        const int b = kt & 1;
        unsigned short* dA = As + (1 - b) * 4096 + wso;
        unsigned short* dB = Bs + (1 - b) * 4096 + wso;
        const size_t ko = (size_t)(kt + 1) * 32;
        gll16(gA + ko, dA); gll16(gA + (size_t)16 * HDIM + ko, dA + 512);
        gll16(gB + ko, dB); gll16(gB + (size_t)16 * HDIM + ko, dB + 512);
        asm volatile("s_waitcnt vmcnt(4)" ::: "memory");
        asm volatile("s_barrier" ::: "memory");
        GEMM_COMPUTE32(As + b * 4096, Bs + b * 4096);
        asm volatile("s_barrier" ::: "memory");
    }
    asm volatile("s_waitcnt vmcnt(0)" ::: "memory");
    asm volatile("s_barrier" ::: "memory");
    GEMM_COMPUTE32(As + ((NK - 1) & 1) * 4096, Bs + ((NK - 1) & 1) * 4096);

    // epilogue: + b1, gelu(erf), -> bf16 h
    float bias[4];
    #pragma unroll
    for (int j = 0; j < 4; j++) bias[j] = b1[e * IDIM + ct * 128 + wn + j * 16 + fr];
    #pragma unroll
    for (int i = 0; i < 4; i++) {
        #pragma unroll
        for (int rg = 0; rg < 4; rg++) {
            const int r = rt * 128 + wm + i * 16 + quad * 4 + rg;
            if (r < ne) {
                unsigned short* hrow = hbuf + (size_t)(off + r) * IDIM + ct * 128 + wn + fr;
                #pragma unroll
                for (int j = 0; j < 4; j++)
                    hrow[j * 16] = f2bf(gelu_f(acc[i][j][rg] + bias[j]));
            }
        }
    }
}

// ---------------- GEMM2: hbuf @ w2bf -> +b2 -> *wt -> eo[t,slot,:] ----------------
__global__ __launch_bounds__(256, 5) void k_gemm2(
    const unsigned short* __restrict__ hbuf, const unsigned short* __restrict__ wbf,
    const float* __restrict__ b2,
    const int* __restrict__ counts, const int* __restrict__ offs,
    const int* __restrict__ rb_e, const int* __restrict__ rb_rt,
    const int* __restrict__ ltok, const float* __restrict__ lwt,
    float* __restrict__ eo)
{
    const int e = rb_e[blockIdx.y];
    if (e < 0) return;
    const int rt = rb_rt[blockIdx.y], ct = blockIdx.x;
    const int ne = counts[e], off = offs[e];
    __shared__ unsigned short As[2 * 128 * 32];
    __shared__ unsigned short Bs[2 * 128 * 32];
    const int tid = threadIdx.x, wid = tid >> 6, lane = tid & 63;
    const int srow = 32 * wid + (lane >> 2);
    const int kswz = ((lane & 3) ^ ((lane >> 3) & 3)) * 8;
    const unsigned short* gA = hbuf + (size_t)(off + rt * 128 + srow) * IDIM + kswz;
    const unsigned short* gB = wbf + (size_t)e * HDIM * IDIM
                             + (size_t)(ct * 128 + srow) * IDIM + kswz;
    const int wso = wid * 1024;

    f32x4 acc[4][4];
    #pragma unroll
    for (int i = 0; i < 4; i++)
        #pragma unroll
        for (int j = 0; j < 4; j++) acc[i][j] = (f32x4){0.f, 0.f, 0.f, 0.f};

    const int wm = (wid & 1) * 64, wn = (wid >> 1) * 64;
    const int fr = lane & 15, quad = lane >> 4;

    const int NK = IDIM / 32;  // 128
    {   // prologue -> buf 0
        unsigned short* dA = As + wso;
        unsigned short* dB = Bs + wso;
        gll16(gA, dA); gll16(gA + (size_t)16 * IDIM, dA + 512);
        gll16(gB, dB); gll16(gB + (size_t)16 * IDIM, dB + 512);
    }
    #pragma unroll 1
    for (int kt = 0; kt < NK - 1; ++kt) {
        const int b = kt & 1;
        unsigned short* dA = As + (1 - b) * 4096 + wso;
        unsigned short* dB = Bs + (1 - b) * 4096 + wso;
        const size_t ko = (size_t)(kt + 1) * 32;
        gll16(gA + ko, dA); gll16(gA + (size_t)16 * IDIM + ko, dA + 512);
        gll16(gB + ko, dB); gll16(gB + (size_t)16 * IDIM + ko, dB + 512);
        asm volatile("s_waitcnt vmcnt(4)" ::: "memory");
        asm volatile("s_barrier" ::: "memory");
        GEMM_COMPUTE32(As + b * 4096, Bs + b * 4096);
        asm volatile("s_barrier" ::: "memory");
    }
    asm volatile("s_waitcnt vmcnt(0)" ::: "memory");
    asm volatile("s_barrier" ::: "memory");
    GEMM_COMPUTE32(As + ((NK - 1) & 1) * 4096, Bs + ((NK - 1) & 1) * 4096);

    // epilogue: + b2, * routing weight, scatter fp32 to eo[token*2+slot]
    float bias[4];
    #pragma unroll
    for (int j = 0; j < 4; j++) bias[j] = b2[e * HDIM + ct * 128 + wn + j * 16 + fr];
    #pragma unroll
    for (int i = 0; i < 4; i++) {
        #pragma unroll
        for (int rg = 0; rg < 4; rg++) {
            const int r = rt * 128 + wm + i * 16 + quad * 4 + rg;
            if (r < ne) {
                const int d = ltok[e * T_TOK + r];
                const float w = lwt[e * T_TOK + r];
                float* erow = eo + (size_t)d * HDIM + ct * 128 + wn + fr;
                #pragma unroll
                for (int j = 0; j < 4; j++)
                    erow[j * 16] = (acc[i][j][rg] + bias[j]) * w;
            }
        }
    }
}

// ---------------- combine + final LN ----------------
__global__ __launch_bounds__(256) void k_final(
    const float* __restrict__ eo, const float* __restrict__ ow, const float* __restrict__ ob,
    float* __restrict__ out)
{
    const int t = blockIdx.x, tid = threadIdx.x;
    const float4 a = *(const float4*)(eo + (size_t)(t * 2 + 0) * HDIM + tid * 4);
    const float4 b = *(const float4*)(eo + (size_t)(t * 2 + 1) * HDIM + tid * 4);
    float c0 = a.x + b.x, c1 = a.y + b.y, c2 = a.z + b.z, c3 = a.w + b.w;
    float s = c0 + c1 + c2 + c3;
    float sq = c0*c0 + c1*c1 + c2*c2 + c3*c3;
    for (int o = 32; o > 0; o >>= 1) { s += __shfl_xor(s, o); sq += __shfl_xor(sq, o); }
    __shared__ float red[8];
    __shared__ float stats[2];
    const int wid = tid >> 6, lane = tid & 63;
    if (lane == 0) { red[wid] = s; red[4 + wid] = sq; }
    __syncthreads();
    if (tid == 0) {
        float S = red[0] + red[1] + red[2] + red[3];
        float Q = red[4] + red[5] + red[6] + red[7];
        float mu = S / (float)HDIM;
        float var = Q / (float)HDIM - mu * mu;
        stats[0] = mu; stats[1] = rsqrtf(var + 1e-5f);
    }
    __syncthreads();
    const float mu = stats[0], rstd = stats[1];
    const float4 w4 = *(const float4*)(ow + tid * 4);
    const float4 b4 = *(const float4*)(ob + tid * 4);
    float4 o;
    o.x = (c0 - mu) * rstd * w4.x + b4.x;
    o.y = (c1 - mu) * rstd * w4.y + b4.y;
    o.z = (c2 - mu) * rstd * w4.z + b4.z;
    o.w = (c3 - mu) * rstd * w4.w + b4.w;
    *(float4*)(out + (size_t)t * HDIM + tid * 4) = o;
}

extern "C" void kernel_launch(void* const* d_in, const int* in_sizes, int n_in,
                              void* d_out, int out_size, void* d_ws, size_t ws_size,
                              hipStream_t stream) {
    const float* x   = (const float*)d_in[0];
    const float* rlw = (const float*)d_in[1];
    const float* rlb = (const float*)d_in[2];
    const float* rw  = (const float*)d_in[3];
    const float* rb  = (const float*)d_in[4];
    const float* elw = (const float*)d_in[5];
    const float* elb = (const float*)d_in[6];
    const float* w1  = (const float*)d_in[7];
    const float* b1  = (const float*)d_in[8];
    const float* w2  = (const float*)d_in[9];
    const float* b2  = (const float*)d_in[10];
    const float* ow  = (const float*)d_in[11];
    const float* ob  = (const float*)d_in[12];
    float* out = (float*)d_out;

    const size_t MB = 1024 * 1024;
    char* ws = (char*)d_ws;
    const bool big = ws_size >= 242 * MB;
    // small (~160.3 MB): wbf1 [0,64) | hbuf/xhat [64,128) | ag+eo share [128,160) | tail
    //   (w2 converted into wbf1 AFTER gemm1 — 256 MB fp32 stream evicts hbuf from L3)
    // big (~241.3 MB):   wbf1 [0,64) | hbuf/xhat [64,128) | wbf2 [128,192) |
    //                    eo [192,224) | ag [224,240.3) | tail — w2 converted up-front.
    unsigned short* wbf1 = (unsigned short*)(ws);
    unsigned short* hbuf = (unsigned short*)(ws + 64 * MB);
    unsigned short* xhat = (unsigned short*)(ws + 64 * MB);
    unsigned short* wbf2 = big ? (unsigned short*)(ws + 128 * MB) : wbf1;
    float* eo            = big ? (float*)(ws + 192 * MB) : (float*)(ws + 128 * MB);
    unsigned short* ag   = big ? (unsigned short*)(ws + 224 * MB)
                               : (unsigned short*)(ws + 128 * MB);
    char* tail           = ws + (big ? 241 * MB : 160 * MB);
    int* ltok            = (int*)(tail);
    float* lwt           = (float*)(tail + 131072);
    int* counts          = (int*)(tail + 262144);
    int* offs            = (int*)(tail + 262144 + 64);
    int* rb_e            = (int*)(tail + 262144 + 128);
    int* rb_rt           = (int*)(tail + 262144 + 512);

    hipMemsetAsync(counts, 0, 8 * sizeof(int), stream);
    // w1 [E][H][I] -> wbf1 [E][I][H] bf16
    k_cvt_t<<<dim3(IDIM / 64, HDIM / 64, NEXP), dim3(256), 0, stream>>>(w1, wbf1, HDIM, IDIM);
    if (big)  // w2 [E][I][H] -> wbf2 [E][H][I] bf16, up-front (keeps hbuf L3-hot later)
        k_cvt_t<<<dim3(HDIM / 64, IDIM / 64, NEXP), dim3(256), 0, stream>>>(w2, wbf2, IDIM, HDIM);
    k_ln_router<<<dim3(T_TOK), dim3(256), 0, stream>>>(x, rlw, rlb, rw, rb, xhat, counts, ltok, lwt);
    k_sched<<<dim3(1), dim3(64), 0, stream>>>(counts, offs, rb_e, rb_rt);
    k_ag_build<<<dim3(32, 4, NEXP), dim3(256), 0, stream>>>(xhat, elw, elb, counts, offs, ltok, ag);
    // grids: x = ct (XCD-affine), y = compacted row-block schedule
    k_gemm1<<<dim3(IDIM / 128, MAXRB), dim3(256), 0, stream>>>(
        ag, wbf1, b1, counts, offs, rb_e, rb_rt, hbuf);
    if (!big)
        k_cvt_t<<<dim3(HDIM / 64, IDIM / 64, NEXP), dim3(256), 0, stream>>>(w2, wbf2, IDIM, HDIM);
    k_gemm2<<<dim3(HDIM / 128, MAXRB), dim3(256), 0, stream>>>(
        hbuf, wbf2, b2, counts, offs, rb_e, rb_rt, ltok, lwt, eo);
    k_final<<<dim3(T_TOK), dim3(256), 0, stream>>>(eo, ow, ob, out);
}